// Round 10
// baseline (324.568 us; speedup 1.0000x reference)
//
#include <hip/hip_runtime.h>
#include <math.h>

#define HD 64
#define WPB 2

typedef unsigned short u16;
typedef unsigned int u32;
typedef __attribute__((ext_vector_type(8))) short short8;
typedef __attribute__((ext_vector_type(4))) float f32x4;

// 1-op bf16 convert (RNE). No builtin on gfx950; VOP3 so both srcs VGPR.
__device__ __forceinline__ u16 f2bf(float f) {
  u32 r;
  asm("v_cvt_pk_bf16_f32 %0, %1, %2" : "=v"(r) : "v"(f), "v"(f));
  return (u16)r;
}
__device__ __forceinline__ float bf2f(u16 x) {
  return __uint_as_float(((u32)x) << 16);
}
// Quadrant swizzle: XOR row bits 2-3 into col bits 4-5. Conflict-free for
// epilogue b16 stores, A-frag ds_read_b128 (2-way), col-mode u16 reads.
// Constant within an i=0..3 epilogue quad -> stores fold to base + i*128B.
__device__ __forceinline__ int uswz(int row, int col) {
  return (row << 6) | (col ^ (((row >> 2) & 3) << 4));
}
__device__ __forceinline__ float rlane(float v, int l) {
  return __uint_as_float(__builtin_amdgcn_readlane(__float_as_uint(v), l));
}
// Wave-local LDS fence: drains outstanding DS ops so a later phase's writes
// cannot overtake an earlier phase's reads (WAR) or miss its writes (RAW).
// R9 post-mortem: fence-free discipline raced intermittently once bank
// conflicts stopped serializing the pipe. Plain lgkmcnt wait, NO
// sched_barrier -> global loads / VALU still schedule across it.
__device__ __forceinline__ void fence() {
  asm volatile("s_waitcnt lgkmcnt(0)" ::: "memory");
}

// read A fragments once per phase (rows clamped to RMAX)
template <int MT, int RMAX>
__device__ __forceinline__ void loadA(const u16* A_, int t, short8* a0, short8* a1) {
  const int q8 = (t >> 4) << 3;
#pragma unroll
  for (int mt = 0; mt < MT; ++mt) {
    int row = mt * 16 + (t & 15);
    row = row > RMAX ? RMAX : row;
    const int idx = uswz(row, q8);
    a0[mt] = *reinterpret_cast<const short8*>(A_ + idx);
    a1[mt] = *reinterpret_cast<const short8*>(A_ + (idx ^ 32));  // swz commutes
  }
}

// one N-half (cols nh*32..nh*32+31) of the 64x64 matmul
template <int MT>
__device__ __forceinline__ void mmh(const short8* a0, const short8* a1,
                                    const u16* __restrict__ WT, f32x4 (*acc)[2],
                                    int t, int nh) {
  const int c15 = t & 15;
  const int q8 = (t >> 4) << 3;
  short8 b[2][2];
#pragma unroll
  for (int n2 = 0; n2 < 2; ++n2) {
    const int nt = nh * 2 + n2;
#pragma unroll
    for (int s = 0; s < 2; ++s)
      b[n2][s] = *reinterpret_cast<const short8*>(WT + (nt * 16 + c15) * 64 + s * 32 + q8);
  }
#pragma unroll
  for (int mt = 0; mt < MT; ++mt) {
#pragma unroll
    for (int n2 = 0; n2 < 2; ++n2)
      acc[mt][n2] = __builtin_amdgcn_mfma_f32_16x16x32_bf16(a0[mt], b[n2][0], acc[mt][n2], 0, 0, 0);
#pragma unroll
    for (int n2 = 0; n2 < 2; ++n2)
      acc[mt][n2] = __builtin_amdgcn_mfma_f32_16x16x32_bf16(a1[mt], b[n2][1], acc[mt][n2], 0, 0, 0);
  }
}

// EPI: 1=store, 2=relu, 3=relu*M (MULT), 4=relu + D (RESID). Bias is folded
// into the accumulator init. In-phase WAR (A-reads vs D-writes) is ordered by
// the MFMA data dependence; cross-phase hazards are fenced by the caller.
template <int MT, int RMAX, int EPI>
__device__ __forceinline__ void run_phase(const u16* A_, u16* D_, const u16* M_,
                                          const u16* __restrict__ WT,
                                          const float* __restrict__ bias, int t,
                                          int rowoff = 0) {
  const int c15 = t & 15, q = t >> 4;
  constexpr int rowlim = (MT == 2) ? 25 : 5;
  short8 a0[MT], a1[MT];
  loadA<MT, RMAX>(A_, t, a0, a1);
#pragma unroll
  for (int nh = 0; nh < 2; ++nh) {
    f32x4 acc[MT][2];
#pragma unroll
    for (int n2 = 0; n2 < 2; ++n2) {
      const int col = (nh * 2 + n2) * 16 + c15;
      const float bb = bias ? bias[col] : 0.0f;
#pragma unroll
      for (int mt = 0; mt < MT; ++mt) acc[mt][n2] = (f32x4){bb, bb, bb, bb};
    }
    mmh<MT>(a0, a1, WT, acc, t, nh);
#pragma unroll
    for (int n2 = 0; n2 < 2; ++n2) {
      const int col = (nh * 2 + n2) * 16 + c15;
#pragma unroll
      for (int mt = 0; mt < MT; ++mt) {
        const int r0 = mt * 16 + q * 4;
        const int bix = uswz(r0 + rowoff, col);  // +i*64 per row (const swizzle)
#pragma unroll
        for (int i = 0; i < 4; ++i) {
          if (r0 + i < rowlim) {
            const int ix = bix + i * 64;
            float v = acc[mt][n2][i];
            if (EPI >= 2) v = fmaxf(v, 0.0f);
            if (EPI == 3) v *= bf2f(M_[ix]);
            if (EPI == 4) v += bf2f(D_[ix]);
            D_[ix] = f2bf(v);
          }
        }
      }
    }
  }
}

// ---- pre-pass: pack weights to bf16 transposed [n][k] ----
__global__ __launch_bounds__(256) void prepack(
    const float* __restrict__ br_w1, const float* __restrict__ br_w2,
    const float* __restrict__ out_w, const float* __restrict__ e_w1,
    const float* __restrict__ e_w2, const float* __restrict__ c_w1,
    const float* __restrict__ v_w1, const float* __restrict__ n_w1,
    const float* __restrict__ n_w2, const float* __restrict__ ic_wef,
    u16* __restrict__ W) {
  const int m = blockIdx.x;
  if (m == 16) {  // ic_wef^T, K padded 12->32 with zeros
    for (int e = threadIdx.x; e < 2048; e += blockDim.x) {
      const int n = e >> 5, k = e & 31;
      W[16 * 4096 + e] = (k < 12) ? f2bf(ic_wef[k * 64 + n]) : (u16)0;
    }
    return;
  }
  const float* src;
  switch (m) {
    case 0: src = br_w1; break;
    case 1: src = br_w1 + 4096; break;
    case 2: src = br_w1 + 8192; break;
    case 3: src = br_w2; break;
    case 4: src = br_w2 + 4096; break;
    case 5: src = br_w2 + 8192; break;
    case 6: src = out_w; break;
    case 7: src = e_w1; break;             // h[row]
    case 8: src = e_w1 + 64 * 64; break;   // h[col]
    case 9: src = e_w1 + 129 * 64; break;  // kemb
    case 10: src = e_w2; break;
    case 11: src = c_w1; break;
    case 12: src = v_w1; break;
    case 13: src = n_w1; break;            // h half
    case 14: src = n_w1 + 64 * 64; break;  // nagg half
    default: src = n_w2; break;
  }
  u16* dst = W + m * 4096;
  for (int e = threadIdx.x; e < 4096; e += blockDim.x) {
    const int n = e >> 6, k = e & 63;
    dst[e] = f2bf(src[k * 64 + n]);
  }
}

__global__ __launch_bounds__(64 * WPB, 4) void egcl_mfma(
    const float* __restrict__ gh, const float* __restrict__ gcoord,
    const float* __restrict__ gvel, const u16* __restrict__ Wg,
    const float* __restrict__ e_w1, const float* __restrict__ e_b1,
    const float* __restrict__ e_b2,
    const float* __restrict__ n_b1, const float* __restrict__ n_b2,
    const float* __restrict__ c_b1, const float* __restrict__ c_w2,
    const float* __restrict__ v_b1, const float* __restrict__ v_w2,
    const float* __restrict__ v_b2,
    const float* __restrict__ ic_pat,
    const float* __restrict__ br_b1, const float* __restrict__ br_b2,
    const float* __restrict__ out_b,
    float* __restrict__ hout, float* __restrict__ cout, int B) {
  // 5120 u16 per wave: H[5][64]@0, K@320, T@1920, U@3520 (each [25][64] swz)
  __shared__ __align__(16) u16 arena[WPB][5120];

  const int t = threadIdx.x & 63;
  const int wv = threadIdx.x >> 6;
  const int g = blockIdx.x * WPB + wv;
  if (g >= B) return;  // waves independent; no block barriers anywhere

  u16* AR = arena[wv];
  u16* H_ = AR;
  u16* K_ = AR + 320;
  u16* T_ = AR + 1920;
  u16* U_ = AR + 3520;
  u16* EFa = T_;  // EF lives in T before T's first matmul use: [25][32] plain
  const int c15 = t & 15, q = t >> 4, q8 = q << 3;
#define WT(m) (Wg + (m) * 4096)

  // ---------------- prologue: inputs ----------------
  float scvreg = 0.0f;
  if (t < 15) scvreg = gcoord[g * 15 + t];
  else if (t >= 16 && t < 31) scvreg = gvel[g * 15 + (t - 16)];

#pragma unroll
  for (int i = 0; i < 5; ++i) H_[uswz(i, t)] = f2bf(gh[(g * 5 + i) * HD + t]);

  // zero EF cols 12..31 (rows 0..24): 250 u32 slots
#pragma unroll
  for (int z = 0; z < 4; ++z) {
    const int e = t + z * 64;
    if (e < 250) {
      const int row = e / 10, cc = 12 + (e % 10) * 2;
      *reinterpret_cast<u32*>(EFa + row * 32 + cc) = 0u;
    }
  }

  float sqcc = 0.0f;  // squared coord-dist for this lane's tuple (radial)
  if (t < 25) {
    const int ti = t / 5, tj = t % 5;
    const float cix = __shfl(scvreg, ti * 3 + 0, 64), ciy = __shfl(scvreg, ti * 3 + 1, 64), ciz = __shfl(scvreg, ti * 3 + 2, 64);
    const float cjx = __shfl(scvreg, tj * 3 + 0, 64), cjy = __shfl(scvreg, tj * 3 + 1, 64), cjz = __shfl(scvreg, tj * 3 + 2, 64);
    const float vix = __shfl(scvreg, 16 + ti * 3 + 0, 64), viy = __shfl(scvreg, 16 + ti * 3 + 1, 64), viz = __shfl(scvreg, 16 + ti * 3 + 2, 64);
    const float vjx = __shfl(scvreg, 16 + tj * 3 + 0, 64), vjy = __shfl(scvreg, 16 + tj * 3 + 1, 64), vjz = __shfl(scvreg, 16 + tj * 3 + 2, 64);
    {
      const float dx = cix - cjx, dy = ciy - cjy, dz = ciz - cjz;
      sqcc = dx * dx + dy * dy + dz * dz;
    }
    auto sd = [](float sq) { return (sq > 0.0f) ? sqrtf(sq) : 0.0f; };
    float sq2;
    const float dcc = sd(sqcc);
    {
      const float dx = vix - vjx, dy = viy - vjy, dz = viz - vjz;
      sq2 = dx * dx + dy * dy + dz * dz;
    }
    const float dvv = sd(sq2);
    {
      const float dx = cix - vjx, dy = ciy - vjy, dz = ciz - vjz;
      sq2 = dx * dx + dy * dy + dz * dz;
    }
    const float dcv = sd(sq2);
    {
      const float dx = cjx - vix, dy = cjy - viy, dz = cjz - viz;
      sq2 = dx * dx + dy * dy + dz * dz;
    }
    const float dvc = sd(sq2);
    auto rbf3 = [&](float d, int base) {
      const float cut = (d <= 10.0f) ? (0.5f * (cosf(d * 0.31415926535897931f) + 1.0f)) : 0.0f;
      const float e = expf(-0.5f * d);
      const float u0 = e - 4.5399929762484854e-05f;
      const float u1 = e - 0.50002270f;
      const float u2 = e - 1.0f;
      const float BETA = 2.2502043f;
      EFa[t * 32 + base + 0] = f2bf((cut * expf(-BETA * u0 * u0) - 0.05f) * (1.0f / 0.15f));
      EFa[t * 32 + base + 1] = f2bf((cut * expf(-BETA * u1 * u1) - 0.05f) * (1.0f / 0.15f));
      EFa[t * 32 + base + 2] = f2bf((cut * expf(-BETA * u2 * u2) - 0.05f) * (1.0f / 0.15f));
    };
    rbf3(dcc, 0);
    rbf3(dvv, 3);
    rbf3(dcv, 6);
    rbf3(dvc, 9);
  }
  fence();  // H/EF writes visible before kemb reads

  // ---------------- kemb = (ef @ ic_wef) * ic_pat[pattern] -> K ------------
  {
    short8 aE[2];
#pragma unroll
    for (int mt = 0; mt < 2; ++mt) {
      int row = mt * 16 + c15;
      row = row > 24 ? 24 : row;
      aE[mt] = *reinterpret_cast<const short8*>(EFa + row * 32 + q8);
    }
    const u16* WTp = Wg + 16 * 4096;
#pragma unroll
    for (int nh = 0; nh < 2; ++nh) {
      f32x4 acc[2][2];
#pragma unroll
      for (int mt = 0; mt < 2; ++mt)
#pragma unroll
        for (int n2 = 0; n2 < 2; ++n2) acc[mt][n2] = (f32x4){0.f, 0.f, 0.f, 0.f};
      short8 b[2];
#pragma unroll
      for (int n2 = 0; n2 < 2; ++n2)
        b[n2] = *reinterpret_cast<const short8*>(WTp + ((nh * 2 + n2) * 16 + c15) * 32 + q8);
#pragma unroll
      for (int mt = 0; mt < 2; ++mt)
#pragma unroll
        for (int n2 = 0; n2 < 2; ++n2)
          acc[mt][n2] = __builtin_amdgcn_mfma_f32_16x16x32_bf16(aE[mt], b[n2], acc[mt][n2], 0, 0, 0);
#pragma unroll
      for (int n2 = 0; n2 < 2; ++n2) {
        const int col = (nh * 2 + n2) * 16 + c15;
        const float p1 = ic_pat[64 + col], p2 = ic_pat[128 + col];
#pragma unroll
        for (int mt = 0; mt < 2; ++mt) {
          const int r0 = mt * 16 + q * 4;
          const int bix = uswz(r0, col);
#pragma unroll
          for (int i = 0; i < 4; ++i) {
            const int row = r0 + i;
            if (row < 25) {
              const bool diag = (row % 6) == 0;  // tuples 0,6,12,18,24
              K_[bix + i * 64] = f2bf(acc[mt][n2][i] * (diag ? p2 : p1));
            }
          }
        }
      }
    }
  }
  fence();

  float svv[4];
  float svc[2][4];

  // ---------------- branch MLPs ----------------
  run_phase<2, 24, 2>(K_, T_, nullptr, WT(1), br_b1 + 64, t); fence();   // k0 L1 -> T
  run_phase<2, 24, 2>(T_, U_, nullptr, WT(4), br_b2 + 64, t); fence();   // k0 -> U
  run_phase<2, 24, 2>(K_, T_, nullptr, WT(2), br_b1 + 128, t); fence();  // k1 L1 -> T
  run_phase<2, 24, 2>(T_, T_, nullptr, WT(5), br_b2 + 128, t); fence();  // k1 -> T (in-place)

  // ---------------- einsum (col mode, j-outer) : mult -> U ----------------
  {
    float mu[25];
#pragma unroll
    for (int p = 0; p < 25; ++p) mu[p] = 0.0f;
#pragma unroll
    for (int j = 0; j < 5; ++j) {
      float k1r[5], k0c[5];
#pragma unroll
      for (int k = 0; k < 5; ++k) k1r[k] = bf2f(T_[uswz(j * 5 + k, t)]);
#pragma unroll
      for (int i = 0; i < 5; ++i) k0c[i] = bf2f(U_[uswz(i * 5 + j, t)]);
#pragma unroll
      for (int i = 0; i < 5; ++i)
#pragma unroll
        for (int k = 0; k < 5; ++k) mu[i * 5 + k] = fmaf(k0c[i], k1r[k], mu[i * 5 + k]);
    }
    fence();  // all T/U reads returned before U overwrite
#pragma unroll
    for (int p = 0; p < 25; ++p) U_[uswz(p, t)] = f2bf(mu[p]);
  }
  fence();

  run_phase<2, 24, 2>(K_, T_, nullptr, WT(0), br_b1, t); fence();        // sm L1 -> T
  run_phase<2, 24, 3>(T_, T_, U_, WT(3), br_b2, t); fence();             // z = relu(sm)*mult -> T
  run_phase<2, 24, 4>(T_, K_, nullptr, WT(6), out_b, t); fence();        // residual -> K
  run_phase<2, 24, 1>(K_, T_, nullptr, WT(9), nullptr, t); fence();      // accC -> T

  // ---------------- fused H-phase: accA -> U r0-4, accB -> U r8-12, VRED ---
  {
    short8 a0[1], a1[1];
    loadA<1, 4>(H_, t, a0, a1);
    float s[4] = {0.f, 0.f, 0.f, 0.f};
#pragma unroll
    for (int nh = 0; nh < 2; ++nh) {
      f32x4 aA[1][2], aB[1][2], aV[1][2];
#pragma unroll
      for (int n2 = 0; n2 < 2; ++n2) {
        aA[0][n2] = (f32x4){0.f, 0.f, 0.f, 0.f};
        aB[0][n2] = (f32x4){0.f, 0.f, 0.f, 0.f};
        const float bv = v_b1[(nh * 2 + n2) * 16 + c15];
        aV[0][n2] = (f32x4){bv, bv, bv, bv};
      }
      mmh<1>(a0, a1, WT(7), aA, t, nh);
      mmh<1>(a0, a1, WT(8), aB, t, nh);
      mmh<1>(a0, a1, WT(12), aV, t, nh);
#pragma unroll
      for (int n2 = 0; n2 < 2; ++n2) {
        const int col = (nh * 2 + n2) * 16 + c15;
        const int r0 = q * 4;
        const int bixA = uswz(r0, col);
        const int bixB = uswz(r0 + 8, col);
        const float w2v = v_w2[col];
#pragma unroll
        for (int i = 0; i < 4; ++i) {
          if (r0 + i < 5) {
            U_[bixA + i * 64] = f2bf(aA[0][n2][i]);
            U_[bixB + i * 64] = f2bf(aB[0][n2][i]);
          }
          s[i] += fmaxf(aV[0][n2][i], 0.0f) * w2v;
        }
      }
    }
#pragma unroll
    for (int i = 0; i < 4; ++i) {
      float ss = s[i];
      ss += __shfl_xor(ss, 1, 64);
      ss += __shfl_xor(ss, 2, 64);
      ss += __shfl_xor(ss, 4, 64);
      ss += __shfl_xor(ss, 8, 64);
      svv[i] = ss;
    }
  }
  fence();

  // ---------------- edge assembly (col mode) ----------------
  {
    float aAc[5], aBc[5];
#pragma unroll
    for (int i = 0; i < 5; ++i) {
      aAc[i] = bf2f(U_[uswz(i, t)]);
      aBc[i] = bf2f(U_[uswz(8 + i, t)]);
    }
    const float eb1v = e_b1[t];
    const float wradv = e_w1[128 * HD + t];
    float ec[20];
#pragma unroll
    for (int p = 0; p < 20; ++p) {
      const int i = p >> 2, jj = p & 3;
      const int j = jj + (jj >= i ? 1 : 0);
      const float radial = rlane(sqcc, i * 5 + j);
      const float cc = bf2f(T_[uswz(i * 5 + j, t)]);
      ec[p] = fmaxf(aAc[i] + aBc[j] + radial * wradv + cc + eb1v, 0.0f);
    }
    fence();  // T/U col reads returned before T overwrite
#pragma unroll
    for (int p = 0; p < 20; ++p) T_[uswz(p, t)] = f2bf(ec[p]);
  }
  fence();

  run_phase<2, 24, 2>(T_, U_, nullptr, WT(10), e_b2, t); fence();        // edge_feat -> U

  // ---------------- nagg -> K rows 0-4 ----------------
#pragma unroll
  for (int i = 0; i < 5; ++i) {
    float na = 0.0f;
#pragma unroll
    for (int jj = 0; jj < 4; ++jj) na += bf2f(U_[uswz(4 * i + jj, t)]);
    K_[uswz(i, t)] = f2bf(na);
  }
  fence();

  // ---------------- c-model (CRED) ----------------
  {
    short8 a0[2], a1[2];
    loadA<2, 24>(U_, t, a0, a1);
    float s[2][4] = {{0.f, 0.f, 0.f, 0.f}, {0.f, 0.f, 0.f, 0.f}};
#pragma unroll
    for (int nh = 0; nh < 2; ++nh) {
      f32x4 acc[2][2];
#pragma unroll
      for (int n2 = 0; n2 < 2; ++n2) {
        const float bv = c_b1[(nh * 2 + n2) * 16 + c15];
#pragma unroll
        for (int mt = 0; mt < 2; ++mt) acc[mt][n2] = (f32x4){bv, bv, bv, bv};
      }
      mmh<2>(a0, a1, WT(11), acc, t, nh);
#pragma unroll
      for (int n2 = 0; n2 < 2; ++n2) {
        const int col = (nh * 2 + n2) * 16 + c15;
        const float w2v = c_w2[col];
#pragma unroll
        for (int mt = 0; mt < 2; ++mt)
#pragma unroll
          for (int i = 0; i < 4; ++i)
            s[mt][i] += fmaxf(acc[mt][n2][i], 0.0f) * w2v;
      }
    }
#pragma unroll
    for (int mt = 0; mt < 2; ++mt)
#pragma unroll
      for (int i = 0; i < 4; ++i) {
        float ss = s[mt][i];
        ss += __shfl_xor(ss, 1, 64);
        ss += __shfl_xor(ss, 2, 64);
        ss += __shfl_xor(ss, 4, 64);
        ss += __shfl_xor(ss, 8, 64);
        svc[mt][i] = ss;
      }
  }

  // ---------------- coord output (VALU only) ----------------
  {
    const float vb2 = v_b2[0];
    float coutreg = 0.0f;
#pragma unroll
    for (int i = 0; i < 5; ++i) {
      const float vmi = rlane(svv[i & 3], (i >> 2) << 4) + vb2;
#pragma unroll
      for (int dd = 0; dd < 3; ++dd) {
        const float ci = rlane(scvreg, i * 3 + dd);
        float s = 0.0f;
#pragma unroll
        for (int jj = 0; jj < 4; ++jj) {
          const int j = jj + (jj >= i ? 1 : 0);
          const int p = i * 4 + jj;
          const float cmp = rlane(svc[p >> 4][p & 3], ((p & 15) >> 2) << 4);
          float tr = (ci - rlane(scvreg, j * 3 + dd)) * cmp;
          tr = fminf(fmaxf(tr, -100.0f), 100.0f);
          s += tr;
        }
        const float val = ci + 0.25f * s + rlane(scvreg, 16 + i * 3 + dd) * vmi;
        if (t == i * 3 + dd) coutreg = val;
      }
    }
    if (t < 15) cout[g * 15 + t] = coutreg;
  }

  // ---------------- node model: L1 = relu(H@W13 + nagg@W14 + n_b1) -> T ----
  {
    short8 a0h[1], a1h[1], a0k[1], a1k[1];
    loadA<1, 4>(H_, t, a0h, a1h);
    loadA<1, 4>(K_, t, a0k, a1k);
#pragma unroll
    for (int nh = 0; nh < 2; ++nh) {
      f32x4 acc[1][2];
#pragma unroll
      for (int n2 = 0; n2 < 2; ++n2) {
        const float nb = n_b1[(nh * 2 + n2) * 16 + c15];
        acc[0][n2] = (f32x4){nb, nb, nb, nb};
      }
      mmh<1>(a0h, a1h, WT(13), acc, t, nh);
      mmh<1>(a0k, a1k, WT(14), acc, t, nh);
#pragma unroll
      for (int n2 = 0; n2 < 2; ++n2) {
        const int col = (nh * 2 + n2) * 16 + c15;
        const int r0 = q * 4;
        const int bix = uswz(r0, col);
#pragma unroll
        for (int i = 0; i < 4; ++i) {
          if (r0 + i < 5) T_[bix + i * 64] = f2bf(fmaxf(acc[0][n2][i], 0.0f));
        }
      }
    }
  }
  fence();

  // ---------------- node model L2 + residual -> hout ----------------
  {
    short8 a0[1], a1[1];
    loadA<1, 4>(T_, t, a0, a1);
#pragma unroll
    for (int nh = 0; nh < 2; ++nh) {
      f32x4 acc[1][2];
#pragma unroll
      for (int n2 = 0; n2 < 2; ++n2) {
        const float nb = n_b2[(nh * 2 + n2) * 16 + c15];
        acc[0][n2] = (f32x4){nb, nb, nb, nb};
      }
      mmh<1>(a0, a1, WT(15), acc, t, nh);
#pragma unroll
      for (int n2 = 0; n2 < 2; ++n2) {
        const int col = (nh * 2 + n2) * 16 + c15;
#pragma unroll
        for (int i = 0; i < 4; ++i) {
          const int row = q * 4 + i;
          if (row < 5) {
            const size_t ix = (size_t)(g * 5 + row) * HD + col;
            hout[ix] = gh[ix] + acc[0][n2][i];
          }
        }
      }
    }
  }
#undef WT
}

extern "C" void kernel_launch(void* const* d_in, const int* in_sizes, int n_in,
                              void* d_out, int out_size, void* d_ws, size_t ws_size,
                              hipStream_t stream) {
  if (n_in < 27) return;
  const float* gh    = (const float*)d_in[0];
  const float* coord = (const float*)d_in[1];
  const float* vel   = (const float*)d_in[2];
  const float* e_w1 = (const float*)d_in[4];
  const float* e_b1 = (const float*)d_in[5];
  const float* e_w2 = (const float*)d_in[6];
  const float* e_b2 = (const float*)d_in[7];
  const float* n_w1 = (const float*)d_in[8];
  const float* n_b1 = (const float*)d_in[9];
  const float* n_w2 = (const float*)d_in[10];
  const float* n_b2 = (const float*)d_in[11];
  const float* c_w1 = (const float*)d_in[12];
  const float* c_b1 = (const float*)d_in[13];
  const float* c_w2 = (const float*)d_in[14];
  const float* v_w1 = (const float*)d_in[15];
  const float* v_b1 = (const float*)d_in[16];
  const float* v_w2 = (const float*)d_in[17];
  const float* v_b2 = (const float*)d_in[18];
  const float* ic_wef = (const float*)d_in[19];
  const float* ic_pat = (const float*)d_in[20];
  const float* br_w1 = (const float*)d_in[21];
  const float* br_b1 = (const float*)d_in[22];
  const float* br_w2 = (const float*)d_in[23];
  const float* br_b2 = (const float*)d_in[24];
  const float* out_w = (const float*)d_in[25];
  const float* out_b = (const float*)d_in[26];

  const int N = in_sizes[0] / HD;  // 100000
  const int B = N / 5;             // 20000 graphs
  float* hout = (float*)d_out;
  float* cout = (float*)d_out + (size_t)N * HD;
  u16* W = (u16*)d_ws;  // 16*4096 + 2048 u16 = 135168 B

  prepack<<<17, 256, 0, stream>>>(br_w1, br_w2, out_w, e_w1, e_w2, c_w1, v_w1,
                                  n_w1, n_w2, ic_wef, W);

  const int blocks = (B + WPB - 1) / WPB;
  egcl_mfma<<<blocks, 64 * WPB, 0, stream>>>(
      gh, coord, vel, W, e_w1, e_b1, e_b2, n_b1, n_b2, c_b1, c_w2, v_b1, v_w2,
      v_b2, ic_pat, br_b1, br_b2, out_b, hout, cout, B);
}

// Round 11
// 252.512 us; speedup vs baseline: 1.2854x; 1.2854x over previous
//
#include <hip/hip_runtime.h>
#include <math.h>

#define HD 64
#define WPB 2  // waves per block; each wave handles TWO graphs

typedef unsigned short u16;
typedef unsigned int u32;
typedef __attribute__((ext_vector_type(8))) short short8;
typedef __attribute__((ext_vector_type(4))) float f32x4;

// 1-op bf16 convert (RNE). No builtin on gfx950; VOP3 so both srcs VGPR.
__device__ __forceinline__ u16 f2bf(float f) {
  u32 r;
  asm("v_cvt_pk_bf16_f32 %0, %1, %2" : "=v"(r) : "v"(f), "v"(f));
  return (u16)r;
}
__device__ __forceinline__ float bf2f(u16 x) {
  return __uint_as_float(((u32)x) << 16);
}
// Quadrant swizzle: XOR row bits 2-3 into col bits 4-5 (validated R10).
__device__ __forceinline__ int uswz(int row, int col) {
  return (row << 6) | (col ^ (((row >> 2) & 3) << 4));
}
__device__ __forceinline__ float rlane(float v, int l) {
  return __uint_as_float(__builtin_amdgcn_readlane(__float_as_uint(v), l));
}
// Wave-local LDS fence (R9 race post-mortem): drains DS ops at buffer-reuse
// boundaries. Plain lgkmcnt wait, no sched_barrier.
__device__ __forceinline__ void fence() {
  asm volatile("s_waitcnt lgkmcnt(0)" ::: "memory");
}

// read A fragments for one graph (MT tiles, rows clamped to RMAX)
template <int MT, int RMAX>
__device__ __forceinline__ void loadA(const u16* A_, int t, short8* a0, short8* a1) {
  const int q8 = (t >> 4) << 3;
#pragma unroll
  for (int mt = 0; mt < MT; ++mt) {
    int row = mt * 16 + (t & 15);
    row = row > RMAX ? RMAX : row;
    const int idx = uswz(row, q8);
    a0[mt] = *reinterpret_cast<const short8*>(A_ + idx);
    a1[mt] = *reinterpret_cast<const short8*>(A_ + (idx ^ 32));
  }
}

// one N-half of the 64x64 matmul; MTT independent A-tiles share B-frags
template <int MTT>
__device__ __forceinline__ void mmh(const short8* a0, const short8* a1,
                                    const u16* __restrict__ WT, f32x4 (*acc)[2],
                                    int t, int nh) {
  const int c15 = t & 15;
  const int q8 = (t >> 4) << 3;
  short8 b[2][2];
#pragma unroll
  for (int n2 = 0; n2 < 2; ++n2) {
    const int nt = nh * 2 + n2;
#pragma unroll
    for (int s = 0; s < 2; ++s)
      b[n2][s] = *reinterpret_cast<const short8*>(WT + (nt * 16 + c15) * 64 + s * 32 + q8);
  }
#pragma unroll
  for (int mt = 0; mt < MTT; ++mt) {
#pragma unroll
    for (int n2 = 0; n2 < 2; ++n2)
      acc[mt][n2] = __builtin_amdgcn_mfma_f32_16x16x32_bf16(a0[mt], b[n2][0], acc[mt][n2], 0, 0, 0);
#pragma unroll
    for (int n2 = 0; n2 < 2; ++n2)
      acc[mt][n2] = __builtin_amdgcn_mfma_f32_16x16x32_bf16(a1[mt], b[n2][1], acc[mt][n2], 0, 0, 0);
  }
}

// two-graph phase: A from {AA,AB}, D to {DA,DB}, shared B-frags/bias.
// EPI: 1=store, 2=relu, 3=relu*M, 4=relu + D. Bias folded into acc init.
template <int MT, int RMAX, int EPI>
__device__ __forceinline__ void run_phase2(const u16* AA, const u16* AB,
                                           u16* DA, u16* DB,
                                           const u16* MA, const u16* MB,
                                           const u16* __restrict__ WT,
                                           const float* __restrict__ bias,
                                           int t, int rowoff = 0) {
  const int c15 = t & 15, q = t >> 4;
  constexpr int rowlim = (MT == 2) ? 25 : 5;
  short8 a0[2 * MT], a1[2 * MT];
  loadA<MT, RMAX>(AA, t, a0, a1);
  loadA<MT, RMAX>(AB, t, a0 + MT, a1 + MT);
#pragma unroll
  for (int nh = 0; nh < 2; ++nh) {
    f32x4 acc[2 * MT][2];
#pragma unroll
    for (int n2 = 0; n2 < 2; ++n2) {
      const int col = (nh * 2 + n2) * 16 + c15;
      const float bb = bias ? bias[col] : 0.0f;
#pragma unroll
      for (int mt = 0; mt < 2 * MT; ++mt) acc[mt][n2] = (f32x4){bb, bb, bb, bb};
    }
    mmh<2 * MT>(a0, a1, WT, acc, t, nh);
#pragma unroll
    for (int n2 = 0; n2 < 2; ++n2) {
      const int col = (nh * 2 + n2) * 16 + c15;
#pragma unroll
      for (int mt = 0; mt < 2 * MT; ++mt) {
        u16* D_ = (mt < MT) ? DA : DB;
        const u16* M_ = (mt < MT) ? MA : MB;
        const int r0 = (mt % MT) * 16 + q * 4;
        const int bix = uswz(r0 + rowoff, col);
#pragma unroll
        for (int i = 0; i < 4; ++i) {
          if (r0 + i < rowlim) {
            const int ix = bix + i * 64;
            float v = acc[mt][n2][i];
            if (EPI >= 2) v = fmaxf(v, 0.0f);
            if (EPI == 3) v *= bf2f(M_[ix]);
            if (EPI == 4) v += bf2f(D_[ix]);
            D_[ix] = f2bf(v);
          }
        }
      }
    }
  }
}

// ---- pre-pass: pack weights to bf16 transposed [n][k] ----
__global__ __launch_bounds__(256) void prepack(
    const float* __restrict__ br_w1, const float* __restrict__ br_w2,
    const float* __restrict__ out_w, const float* __restrict__ e_w1,
    const float* __restrict__ e_w2, const float* __restrict__ c_w1,
    const float* __restrict__ v_w1, const float* __restrict__ n_w1,
    const float* __restrict__ n_w2, const float* __restrict__ ic_wef,
    u16* __restrict__ W) {
  const int m = blockIdx.x;
  if (m == 16) {  // ic_wef^T, K padded 12->32 with zeros
    for (int e = threadIdx.x; e < 2048; e += blockDim.x) {
      const int n = e >> 5, k = e & 31;
      W[16 * 4096 + e] = (k < 12) ? f2bf(ic_wef[k * 64 + n]) : (u16)0;
    }
    return;
  }
  const float* src;
  switch (m) {
    case 0: src = br_w1; break;
    case 1: src = br_w1 + 4096; break;
    case 2: src = br_w1 + 8192; break;
    case 3: src = br_w2; break;
    case 4: src = br_w2 + 4096; break;
    case 5: src = br_w2 + 8192; break;
    case 6: src = out_w; break;
    case 7: src = e_w1; break;             // h[row]
    case 8: src = e_w1 + 64 * 64; break;   // h[col]
    case 9: src = e_w1 + 129 * 64; break;  // kemb
    case 10: src = e_w2; break;
    case 11: src = c_w1; break;
    case 12: src = v_w1; break;
    case 13: src = n_w1; break;            // h half
    case 14: src = n_w1 + 64 * 64; break;  // nagg half
    default: src = n_w2; break;
  }
  u16* dst = W + m * 4096;
  for (int e = threadIdx.x; e < 4096; e += blockDim.x) {
    const int n = e >> 6, k = e & 63;
    dst[e] = f2bf(src[k * 64 + n]);
  }
}

__global__ __launch_bounds__(64 * WPB, 2) void egcl_mfma(
    const float* __restrict__ gh, const float* __restrict__ gcoord,
    const float* __restrict__ gvel, const u16* __restrict__ Wg,
    const float* __restrict__ e_w1, const float* __restrict__ e_b1,
    const float* __restrict__ e_b2,
    const float* __restrict__ n_b1, const float* __restrict__ n_b2,
    const float* __restrict__ c_b1, const float* __restrict__ c_w2,
    const float* __restrict__ v_b1, const float* __restrict__ v_w2,
    const float* __restrict__ v_b2,
    const float* __restrict__ ic_pat,
    const float* __restrict__ br_b1, const float* __restrict__ br_b2,
    const float* __restrict__ out_b,
    float* __restrict__ hout, float* __restrict__ cout, int B) {
  // per wave: HA@0 HB@320 | KA@640 KB@2240 | TA@3840 TB@5440 | UA@7040 UB@8640
  __shared__ __align__(16) u16 arena[WPB][10240];

  const int t = threadIdx.x & 63;
  const int wv = threadIdx.x >> 6;
  const int gA = (blockIdx.x * WPB + wv) * 2;
  if (gA >= B) return;
  int gB = gA + 1;
  if (gB >= B) gB = gA;  // duplicate work, identical writes: benign

  u16* AR = arena[wv];
  u16* HA = AR;           u16* HB = AR + 320;
  u16* KA = AR + 640;     u16* KB = AR + 2240;
  u16* TA = AR + 3840;    u16* TB = AR + 5440;
  u16* UA = AR + 7040;    u16* UB = AR + 8640;
  u16* EFa = TA;  // EF staging lives in T buffers pre-first-use
  u16* EFb = TB;
  const int c15 = t & 15, q = t >> 4, q8 = q << 3;
#define WT(m) (Wg + (m) * 4096)

  // ---------------- prologue: inputs ----------------
  // scvreg lanes: 0-14 coordA, 16-30 velA, 32-46 coordB, 48-62 velB
  float scvreg = 0.0f;
  if (t < 15) scvreg = gcoord[gA * 15 + t];
  else if (t >= 16 && t < 31) scvreg = gvel[gA * 15 + (t - 16)];
  else if (t >= 32 && t < 47) scvreg = gcoord[gB * 15 + (t - 32)];
  else if (t >= 48 && t < 63) scvreg = gvel[gB * 15 + (t - 48)];

#pragma unroll
  for (int i = 0; i < 5; ++i) {
    HA[uswz(i, t)] = f2bf(gh[(gA * 5 + i) * HD + t]);
    HB[uswz(i, t)] = f2bf(gh[(gB * 5 + i) * HD + t]);
  }

  // zero EF cols 12..31 for both graphs (2 x 250 u32 slots)
#pragma unroll
  for (int z = 0; z < 8; ++z) {
    const int e = t + z * 64;
    if (e < 500) {
      const int gsel = e >= 250;
      const int ee = e - gsel * 250;
      const int row = ee / 10, cc = 12 + (ee % 10) * 2;
      *reinterpret_cast<u32*>((gsel ? EFb : EFa) + row * 32 + cc) = 0u;
    }
  }

  // RBF: lanes 0-24 = graph A tuples, lanes 32-56 = graph B tuples
  float sqcc = 0.0f;
  {
    const int lb = (t >= 32) ? 32 : 0;
    const int tt = t - lb;
    if (tt < 25) {
      u16* EF = lb ? EFb : EFa;
      const int ti = tt / 5, tj = tt % 5;
      const float cix = __shfl(scvreg, lb + ti * 3 + 0, 64), ciy = __shfl(scvreg, lb + ti * 3 + 1, 64), ciz = __shfl(scvreg, lb + ti * 3 + 2, 64);
      const float cjx = __shfl(scvreg, lb + tj * 3 + 0, 64), cjy = __shfl(scvreg, lb + tj * 3 + 1, 64), cjz = __shfl(scvreg, lb + tj * 3 + 2, 64);
      const float vix = __shfl(scvreg, lb + 16 + ti * 3 + 0, 64), viy = __shfl(scvreg, lb + 16 + ti * 3 + 1, 64), viz = __shfl(scvreg, lb + 16 + ti * 3 + 2, 64);
      const float vjx = __shfl(scvreg, lb + 16 + tj * 3 + 0, 64), vjy = __shfl(scvreg, lb + 16 + tj * 3 + 1, 64), vjz = __shfl(scvreg, lb + 16 + tj * 3 + 2, 64);
      {
        const float dx = cix - cjx, dy = ciy - cjy, dz = ciz - cjz;
        sqcc = dx * dx + dy * dy + dz * dz;
      }
      auto sd = [](float sq) { return (sq > 0.0f) ? sqrtf(sq) : 0.0f; };
      float sq2;
      const float dcc = sd(sqcc);
      {
        const float dx = vix - vjx, dy = viy - vjy, dz = viz - vjz;
        sq2 = dx * dx + dy * dy + dz * dz;
      }
      const float dvv = sd(sq2);
      {
        const float dx = cix - vjx, dy = ciy - vjy, dz = ciz - vjz;
        sq2 = dx * dx + dy * dy + dz * dz;
      }
      const float dcv = sd(sq2);
      {
        const float dx = cjx - vix, dy = cjy - viy, dz = cjz - viz;
        sq2 = dx * dx + dy * dy + dz * dz;
      }
      const float dvc = sd(sq2);
      auto rbf3 = [&](float d, int base) {
        const float cut = (d <= 10.0f) ? (0.5f * (cosf(d * 0.31415926535897931f) + 1.0f)) : 0.0f;
        const float e = expf(-0.5f * d);
        const float u0 = e - 4.5399929762484854e-05f;
        const float u1 = e - 0.50002270f;
        const float u2 = e - 1.0f;
        const float BETA = 2.2502043f;
        EF[tt * 32 + base + 0] = f2bf((cut * expf(-BETA * u0 * u0) - 0.05f) * (1.0f / 0.15f));
        EF[tt * 32 + base + 1] = f2bf((cut * expf(-BETA * u1 * u1) - 0.05f) * (1.0f / 0.15f));
        EF[tt * 32 + base + 2] = f2bf((cut * expf(-BETA * u2 * u2) - 0.05f) * (1.0f / 0.15f));
      };
      rbf3(dcc, 0);
      rbf3(dvv, 3);
      rbf3(dcv, 6);
      rbf3(dvc, 9);
    }
  }
  fence();  // H/EF writes visible before kemb reads

  // ---------------- kemb (both graphs) -> KA/KB ----------------
  {
    short8 aE[4];
#pragma unroll
    for (int gsel = 0; gsel < 2; ++gsel) {
      const u16* EF = gsel ? EFb : EFa;
#pragma unroll
      for (int mt = 0; mt < 2; ++mt) {
        int row = mt * 16 + c15;
        row = row > 24 ? 24 : row;
        aE[gsel * 2 + mt] = *reinterpret_cast<const short8*>(EF + row * 32 + q8);
      }
    }
    const u16* WTp = Wg + 16 * 4096;
#pragma unroll
    for (int nh = 0; nh < 2; ++nh) {
      f32x4 acc[4][2];
#pragma unroll
      for (int mt = 0; mt < 4; ++mt)
#pragma unroll
        for (int n2 = 0; n2 < 2; ++n2) acc[mt][n2] = (f32x4){0.f, 0.f, 0.f, 0.f};
      short8 b[2];
#pragma unroll
      for (int n2 = 0; n2 < 2; ++n2)
        b[n2] = *reinterpret_cast<const short8*>(WTp + ((nh * 2 + n2) * 16 + c15) * 32 + q8);
#pragma unroll
      for (int mt = 0; mt < 4; ++mt)
#pragma unroll
        for (int n2 = 0; n2 < 2; ++n2)
          acc[mt][n2] = __builtin_amdgcn_mfma_f32_16x16x32_bf16(aE[mt], b[n2], acc[mt][n2], 0, 0, 0);
#pragma unroll
      for (int n2 = 0; n2 < 2; ++n2) {
        const int col = (nh * 2 + n2) * 16 + c15;
        const float p1 = ic_pat[64 + col], p2 = ic_pat[128 + col];
#pragma unroll
        for (int mt = 0; mt < 4; ++mt) {
          u16* K_ = (mt < 2) ? KA : KB;
          const int r0 = (mt & 1) * 16 + q * 4;
          const int bix = uswz(r0, col);
#pragma unroll
          for (int i = 0; i < 4; ++i) {
            const int row = r0 + i;
            if (row < 25) {
              const bool diag = (row % 6) == 0;
              K_[bix + i * 64] = f2bf(acc[mt][n2][i] * (diag ? p2 : p1));
            }
          }
        }
      }
    }
  }
  fence();

  float svv[2][4];
  float svc[4][4];

  // ---------------- branch MLPs (both graphs per phase) ----------------
  run_phase2<2, 24, 2>(KA, KB, TA, TB, nullptr, nullptr, WT(1), br_b1 + 64, t); fence();
  run_phase2<2, 24, 2>(TA, TB, UA, UB, nullptr, nullptr, WT(4), br_b2 + 64, t); fence();
  run_phase2<2, 24, 2>(KA, KB, TA, TB, nullptr, nullptr, WT(2), br_b1 + 128, t); fence();
  run_phase2<2, 24, 2>(TA, TB, TA, TB, nullptr, nullptr, WT(5), br_b2 + 128, t); fence();

  // ---------------- einsum per graph: mult -> U ----------------
#pragma unroll 1
  for (int gsel = 0; gsel < 2; ++gsel) {
    const u16* Tg = gsel ? TB : TA;
    u16* Ug = gsel ? UB : UA;
    float mu[25];
#pragma unroll
    for (int p = 0; p < 25; ++p) mu[p] = 0.0f;
#pragma unroll
    for (int j = 0; j < 5; ++j) {
      float k1r[5], k0c[5];
#pragma unroll
      for (int k = 0; k < 5; ++k) k1r[k] = bf2f(Tg[uswz(j * 5 + k, t)]);
#pragma unroll
      for (int i = 0; i < 5; ++i) k0c[i] = bf2f(Ug[uswz(i * 5 + j, t)]);
#pragma unroll
      for (int i = 0; i < 5; ++i)
#pragma unroll
        for (int k = 0; k < 5; ++k) mu[i * 5 + k] = fmaf(k0c[i], k1r[k], mu[i * 5 + k]);
    }
    fence();  // reads returned before overwrite
#pragma unroll
    for (int p = 0; p < 25; ++p) Ug[uswz(p, t)] = f2bf(mu[p]);
  }
  fence();

  run_phase2<2, 24, 2>(KA, KB, TA, TB, nullptr, nullptr, WT(0), br_b1, t); fence();
  run_phase2<2, 24, 3>(TA, TB, TA, TB, UA, UB, WT(3), br_b2, t); fence();
  run_phase2<2, 24, 4>(TA, TB, KA, KB, nullptr, nullptr, WT(6), out_b, t); fence();
  run_phase2<2, 24, 1>(KA, KB, TA, TB, nullptr, nullptr, WT(9), nullptr, t); fence();

  // ------- fused H-phase: accA -> U r0-4, accB -> U r8-12, VRED (both) -----
  {
    short8 a0[2], a1[2];
    loadA<1, 4>(HA, t, a0, a1);
    loadA<1, 4>(HB, t, a0 + 1, a1 + 1);
    float s[2][4] = {{0.f, 0.f, 0.f, 0.f}, {0.f, 0.f, 0.f, 0.f}};
#pragma unroll
    for (int nh = 0; nh < 2; ++nh) {
      f32x4 aA[2][2], aB[2][2], aV[2][2];
#pragma unroll
      for (int n2 = 0; n2 < 2; ++n2) {
        const float bv = v_b1[(nh * 2 + n2) * 16 + c15];
#pragma unroll
        for (int m2 = 0; m2 < 2; ++m2) {
          aA[m2][n2] = (f32x4){0.f, 0.f, 0.f, 0.f};
          aB[m2][n2] = (f32x4){0.f, 0.f, 0.f, 0.f};
          aV[m2][n2] = (f32x4){bv, bv, bv, bv};
        }
      }
      mmh<2>(a0, a1, WT(7), aA, t, nh);
      mmh<2>(a0, a1, WT(8), aB, t, nh);
      mmh<2>(a0, a1, WT(12), aV, t, nh);
#pragma unroll
      for (int n2 = 0; n2 < 2; ++n2) {
        const int col = (nh * 2 + n2) * 16 + c15;
        const int r0 = q * 4;
        const float w2v = v_w2[col];
#pragma unroll
        for (int gsel = 0; gsel < 2; ++gsel) {
          u16* Ug = gsel ? UB : UA;
          const int bixA = uswz(r0, col);
          const int bixB = uswz(r0 + 8, col);
#pragma unroll
          for (int i = 0; i < 4; ++i) {
            if (r0 + i < 5) {
              Ug[bixA + i * 64] = f2bf(aA[gsel][n2][i]);
              Ug[bixB + i * 64] = f2bf(aB[gsel][n2][i]);
            }
            s[gsel][i] += fmaxf(aV[gsel][n2][i], 0.0f) * w2v;
          }
        }
      }
    }
#pragma unroll
    for (int gsel = 0; gsel < 2; ++gsel)
#pragma unroll
      for (int i = 0; i < 4; ++i) {
        float ss = s[gsel][i];
        ss += __shfl_xor(ss, 1, 64);
        ss += __shfl_xor(ss, 2, 64);
        ss += __shfl_xor(ss, 4, 64);
        ss += __shfl_xor(ss, 8, 64);
        svv[gsel][i] = ss;
      }
  }
  fence();

  // ---------------- edge assembly per graph ----------------
#pragma unroll 1
  for (int gsel = 0; gsel < 2; ++gsel) {
    const int lb = gsel * 32;
    const u16* Ug = gsel ? UB : UA;
    u16* Tg = gsel ? TB : TA;
    float aAc[5], aBc[5];
#pragma unroll
    for (int i = 0; i < 5; ++i) {
      aAc[i] = bf2f(Ug[uswz(i, t)]);
      aBc[i] = bf2f(Ug[uswz(8 + i, t)]);
    }
    const float eb1v = e_b1[t];
    const float wradv = e_w1[128 * HD + t];
    float ec[20];
#pragma unroll
    for (int p = 0; p < 20; ++p) {
      const int i = p >> 2, jj = p & 3;
      const int j = jj + (jj >= i ? 1 : 0);
      const float radial = rlane(sqcc, lb + i * 5 + j);
      const float cc = bf2f(Tg[uswz(i * 5 + j, t)]);
      ec[p] = fmaxf(aAc[i] + aBc[j] + radial * wradv + cc + eb1v, 0.0f);
    }
    fence();  // reads returned before Tg overwrite
#pragma unroll
    for (int p = 0; p < 20; ++p) Tg[uswz(p, t)] = f2bf(ec[p]);
  }
  fence();

  run_phase2<2, 24, 2>(TA, TB, UA, UB, nullptr, nullptr, WT(10), e_b2, t); fence();

  // ---------------- nagg per graph -> K rows 0-4 ----------------
#pragma unroll
  for (int gsel = 0; gsel < 2; ++gsel) {
    const u16* Ug = gsel ? UB : UA;
    u16* Kg = gsel ? KB : KA;
#pragma unroll
    for (int i = 0; i < 5; ++i) {
      float na = 0.0f;
#pragma unroll
      for (int jj = 0; jj < 4; ++jj) na += bf2f(Ug[uswz(4 * i + jj, t)]);
      Kg[uswz(i, t)] = f2bf(na);
    }
  }
  fence();

  // ---------------- c-model (CRED, both graphs) ----------------
  {
    short8 a0[4], a1[4];
    loadA<2, 24>(UA, t, a0, a1);
    loadA<2, 24>(UB, t, a0 + 2, a1 + 2);
    float s[4][4];
#pragma unroll
    for (int mt = 0; mt < 4; ++mt)
#pragma unroll
      for (int i = 0; i < 4; ++i) s[mt][i] = 0.0f;
#pragma unroll
    for (int nh = 0; nh < 2; ++nh) {
      f32x4 acc[4][2];
#pragma unroll
      for (int n2 = 0; n2 < 2; ++n2) {
        const float bv = c_b1[(nh * 2 + n2) * 16 + c15];
#pragma unroll
        for (int mt = 0; mt < 4; ++mt) acc[mt][n2] = (f32x4){bv, bv, bv, bv};
      }
      mmh<4>(a0, a1, WT(11), acc, t, nh);
#pragma unroll
      for (int n2 = 0; n2 < 2; ++n2) {
        const int col = (nh * 2 + n2) * 16 + c15;
        const float w2v = c_w2[col];
#pragma unroll
        for (int mt = 0; mt < 4; ++mt)
#pragma unroll
          for (int i = 0; i < 4; ++i)
            s[mt][i] += fmaxf(acc[mt][n2][i], 0.0f) * w2v;
      }
    }
#pragma unroll
    for (int mt = 0; mt < 4; ++mt)
#pragma unroll
      for (int i = 0; i < 4; ++i) {
        float ss = s[mt][i];
        ss += __shfl_xor(ss, 1, 64);
        ss += __shfl_xor(ss, 2, 64);
        ss += __shfl_xor(ss, 4, 64);
        ss += __shfl_xor(ss, 8, 64);
        svc[mt][i] = ss;
      }
  }

  // ---------------- coord output (both graphs, VALU only) ----------------
  {
    const float vb2 = v_b2[0];
    float coutreg = 0.0f;
#pragma unroll
    for (int gsel = 0; gsel < 2; ++gsel) {
      const int lb = gsel * 32;
#pragma unroll
      for (int i = 0; i < 5; ++i) {
        const float vmi = rlane(svv[gsel][i & 3], (i >> 2) << 4) + vb2;
#pragma unroll
        for (int dd = 0; dd < 3; ++dd) {
          const float ci = rlane(scvreg, lb + i * 3 + dd);
          float s = 0.0f;
#pragma unroll
          for (int jj = 0; jj < 4; ++jj) {
            const int j = jj + (jj >= i ? 1 : 0);
            const int p = i * 4 + jj;
            const float cmp = rlane(svc[gsel * 2 + (p >> 4)][p & 3], ((p & 15) >> 2) << 4);
            float tr = (ci - rlane(scvreg, lb + j * 3 + dd)) * cmp;
            tr = fminf(fmaxf(tr, -100.0f), 100.0f);
            s += tr;
          }
          const float val = ci + 0.25f * s + rlane(scvreg, lb + 16 + i * 3 + dd) * vmi;
          if (t == lb + i * 3 + dd) coutreg = val;
        }
      }
    }
    if (t < 15) cout[gA * 15 + t] = coutreg;
    else if (t >= 32 && t < 47) cout[gB * 15 + (t - 32)] = coutreg;
  }

  // ---------------- node model L1 (both graphs) -> T rows 0-4 ----------------
  {
    short8 a0h[2], a1h[2], a0k[2], a1k[2];
    loadA<1, 4>(HA, t, a0h, a1h);
    loadA<1, 4>(HB, t, a0h + 1, a1h + 1);
    loadA<1, 4>(KA, t, a0k, a1k);
    loadA<1, 4>(KB, t, a0k + 1, a1k + 1);
#pragma unroll
    for (int nh = 0; nh < 2; ++nh) {
      f32x4 acc[2][2];
#pragma unroll
      for (int n2 = 0; n2 < 2; ++n2) {
        const float nb = n_b1[(nh * 2 + n2) * 16 + c15];
        acc[0][n2] = (f32x4){nb, nb, nb, nb};
        acc[1][n2] = (f32x4){nb, nb, nb, nb};
      }
      mmh<2>(a0h, a1h, WT(13), acc, t, nh);
      mmh<2>(a0k, a1k, WT(14), acc, t, nh);
#pragma unroll
      for (int n2 = 0; n2 < 2; ++n2) {
        const int col = (nh * 2 + n2) * 16 + c15;
        const int r0 = q * 4;
        const int bix = uswz(r0, col);
#pragma unroll
        for (int gsel = 0; gsel < 2; ++gsel) {
          u16* Tg = gsel ? TB : TA;
#pragma unroll
          for (int i = 0; i < 4; ++i) {
            if (r0 + i < 5) Tg[bix + i * 64] = f2bf(fmaxf(acc[gsel][n2][i], 0.0f));
          }
        }
      }
    }
  }
  fence();

  // ---------------- node model L2 + residual -> hout (both graphs) ----------
  {
    short8 a0[2], a1[2];
    loadA<1, 4>(TA, t, a0, a1);
    loadA<1, 4>(TB, t, a0 + 1, a1 + 1);
#pragma unroll
    for (int nh = 0; nh < 2; ++nh) {
      f32x4 acc[2][2];
#pragma unroll
      for (int n2 = 0; n2 < 2; ++n2) {
        const float nb = n_b2[(nh * 2 + n2) * 16 + c15];
        acc[0][n2] = (f32x4){nb, nb, nb, nb};
        acc[1][n2] = (f32x4){nb, nb, nb, nb};
      }
      mmh<2>(a0, a1, WT(15), acc, t, nh);
#pragma unroll
      for (int n2 = 0; n2 < 2; ++n2) {
        const int col = (nh * 2 + n2) * 16 + c15;
#pragma unroll
        for (int gsel = 0; gsel < 2; ++gsel) {
          const int gg = gsel ? gB : gA;
#pragma unroll
          for (int i = 0; i < 4; ++i) {
            const int row = q * 4 + i;
            if (row < 5) {
              const size_t ix = (size_t)(gg * 5 + row) * HD + col;
              hout[ix] = gh[ix] + acc[gsel][n2][i];
            }
          }
        }
      }
    }
  }
#undef WT
}

extern "C" void kernel_launch(void* const* d_in, const int* in_sizes, int n_in,
                              void* d_out, int out_size, void* d_ws, size_t ws_size,
                              hipStream_t stream) {
  if (n_in < 27) return;
  const float* gh    = (const float*)d_in[0];
  const float* coord = (const float*)d_in[1];
  const float* vel   = (const float*)d_in[2];
  const float* e_w1 = (const float*)d_in[4];
  const float* e_b1 = (const float*)d_in[5];
  const float* e_w2 = (const float*)d_in[6];
  const float* e_b2 = (const float*)d_in[7];
  const float* n_w1 = (const float*)d_in[8];
  const float* n_b1 = (const float*)d_in[9];
  const float* n_w2 = (const float*)d_in[10];
  const float* n_b2 = (const float*)d_in[11];
  const float* c_w1 = (const float*)d_in[12];
  const float* c_b1 = (const float*)d_in[13];
  const float* c_w2 = (const float*)d_in[14];
  const float* v_w1 = (const float*)d_in[15];
  const float* v_b1 = (const float*)d_in[16];
  const float* v_w2 = (const float*)d_in[17];
  const float* v_b2 = (const float*)d_in[18];
  const float* ic_wef = (const float*)d_in[19];
  const float* ic_pat = (const float*)d_in[20];
  const float* br_w1 = (const float*)d_in[21];
  const float* br_b1 = (const float*)d_in[22];
  const float* br_w2 = (const float*)d_in[23];
  const float* br_b2 = (const float*)d_in[24];
  const float* out_w = (const float*)d_in[25];
  const float* out_b = (const float*)d_in[26];

  const int N = in_sizes[0] / HD;  // 100000
  const int B = N / 5;             // 20000 graphs
  float* hout = (float*)d_out;
  float* cout = (float*)d_out + (size_t)N * HD;
  u16* W = (u16*)d_ws;  // 16*4096 + 2048 u16 = 135168 B

  prepack<<<17, 256, 0, stream>>>(br_w1, br_w2, out_w, e_w1, e_w2, c_w1, v_w1,
                                  n_w1, n_w2, ic_wef, W);

  const int gpb = WPB * 2;  // graphs per block
  const int blocks = (B + gpb - 1) / gpb;
  egcl_mfma<<<blocks, 64 * WPB, 0, stream>>>(
      gh, coord, vel, W, e_w1, e_b1, e_b2, n_b1, n_b2, c_b1, c_w2, v_b1, v_w2,
      v_b2, ic_pat, br_b1, br_b2, out_b, hout, cout, B);
}

// Round 12
// 245.967 us; speedup vs baseline: 1.3196x; 1.0266x over previous
//
#include <hip/hip_runtime.h>
#include <math.h>

#define HD 64
#define WPB 2  // waves per block; each wave handles TWO graphs

typedef unsigned short u16;
typedef unsigned int u32;
typedef __attribute__((ext_vector_type(8))) short short8;
typedef __attribute__((ext_vector_type(4))) float f32x4;

__device__ __forceinline__ u16 f2bf(float f) {
  u32 r;
  asm("v_cvt_pk_bf16_f32 %0, %1, %2" : "=v"(r) : "v"(f), "v"(f));
  return (u16)r;
}
// pack two floats -> 2 bf16 (lo = first arg)
__device__ __forceinline__ u32 pk2(float lo, float hi) {
  u32 r;
  asm("v_cvt_pk_bf16_f32 %0, %1, %2" : "=v"(r) : "v"(lo), "v"(hi));
  return r;
}
__device__ __forceinline__ float bf2f(u16 x) {
  return __uint_as_float(((u32)x) << 16);
}
// Quadrant swizzle (validated R10): XOR row bits 2-3 into col bits 4-5.
__device__ __forceinline__ int uswz(int row, int col) {
  return (row << 6) | (col ^ (((row >> 2) & 3) << 4));
}
__device__ __forceinline__ float rlane(float v, int l) {
  return __uint_as_float(__builtin_amdgcn_readlane(__float_as_uint(v), l));
}
// Wave-local LDS fence (R9 race post-mortem). Plain lgkmcnt wait.
__device__ __forceinline__ void fence() {
  asm volatile("s_waitcnt lgkmcnt(0)" ::: "memory");
}

template <int MT, int RMAX>
__device__ __forceinline__ void loadA(const u16* A_, int t, short8* a0, short8* a1) {
  const int q8 = (t >> 4) << 3;
#pragma unroll
  for (int mt = 0; mt < MT; ++mt) {
    int row = mt * 16 + (t & 15);
    row = row > RMAX ? RMAX : row;
    const int idx = uswz(row, q8);
    a0[mt] = *reinterpret_cast<const short8*>(A_ + idx);
    a1[mt] = *reinterpret_cast<const short8*>(A_ + (idx ^ 32));
  }
}

template <int MTT>
__device__ __forceinline__ void mmh(const short8* a0, const short8* a1,
                                    const u16* __restrict__ WT, f32x4 (*acc)[2],
                                    int t, int nh) {
  const int c15 = t & 15;
  const int q8 = (t >> 4) << 3;
  short8 b[2][2];
#pragma unroll
  for (int n2 = 0; n2 < 2; ++n2) {
    const int nt = nh * 2 + n2;
#pragma unroll
    for (int s = 0; s < 2; ++s)
      b[n2][s] = *reinterpret_cast<const short8*>(WT + (nt * 16 + c15) * 64 + s * 32 + q8);
  }
#pragma unroll
  for (int mt = 0; mt < MTT; ++mt) {
#pragma unroll
    for (int n2 = 0; n2 < 2; ++n2)
      acc[mt][n2] = __builtin_amdgcn_mfma_f32_16x16x32_bf16(a0[mt], b[n2][0], acc[mt][n2], 0, 0, 0);
#pragma unroll
    for (int n2 = 0; n2 < 2; ++n2)
      acc[mt][n2] = __builtin_amdgcn_mfma_f32_16x16x32_bf16(a1[mt], b[n2][1], acc[mt][n2], 0, 0, 0);
  }
}

// two-graph phase; PF = next-phase weight matrix (8KB) L1-prefetch.
template <int MT, int RMAX, int EPI>
__device__ __forceinline__ void run_phase2(const u16* AA, const u16* AB,
                                           u16* DA, u16* DB,
                                           const u16* MA, const u16* MB,
                                           const u16* __restrict__ WT,
                                           const float* __restrict__ bias,
                                           const u16* __restrict__ PF,
                                           u32& pfa, int t, int rowoff = 0) {
  const int c15 = t & 15, q = t >> 4;
  constexpr int rowlim = (MT == 2) ? 25 : 5;
  const u32 pfv = reinterpret_cast<const u32*>(PF)[t * 32];  // 128B/lane = 8KB
  short8 a0[2 * MT], a1[2 * MT];
  loadA<MT, RMAX>(AA, t, a0, a1);
  loadA<MT, RMAX>(AB, t, a0 + MT, a1 + MT);
#pragma unroll
  for (int nh = 0; nh < 2; ++nh) {
    f32x4 acc[2 * MT][2];
#pragma unroll
    for (int n2 = 0; n2 < 2; ++n2) {
      const int col = (nh * 2 + n2) * 16 + c15;
      const float bb = bias ? bias[col] : 0.0f;
#pragma unroll
      for (int mt = 0; mt < 2 * MT; ++mt) acc[mt][n2] = (f32x4){bb, bb, bb, bb};
    }
    mmh<2 * MT>(a0, a1, WT, acc, t, nh);
#pragma unroll
    for (int n2 = 0; n2 < 2; ++n2) {
      const int col = (nh * 2 + n2) * 16 + c15;
#pragma unroll
      for (int mt = 0; mt < 2 * MT; ++mt) {
        u16* D_ = (mt < MT) ? DA : DB;
        const u16* M_ = (mt < MT) ? MA : MB;
        const int r0 = (mt % MT) * 16 + q * 4;
        const int bix = uswz(r0 + rowoff, col);
#pragma unroll
        for (int i = 0; i < 4; ++i) {
          if (r0 + i < rowlim) {
            const int ix = bix + i * 64;
            float v = acc[mt][n2][i];
            if (EPI >= 2) v = fmaxf(v, 0.0f);
            if (EPI == 3) v *= bf2f(M_[ix]);
            if (EPI == 4) v += bf2f(D_[ix]);
            D_[ix] = f2bf(v);
          }
        }
      }
    }
  }
  pfa ^= pfv;  // defer vmcnt wait to phase end; kept live via B==-7 sink
}

// ---- pre-pass: pack weights to bf16 transposed [n][k] ----
__global__ __launch_bounds__(256) void prepack(
    const float* __restrict__ br_w1, const float* __restrict__ br_w2,
    const float* __restrict__ out_w, const float* __restrict__ e_w1,
    const float* __restrict__ e_w2, const float* __restrict__ c_w1,
    const float* __restrict__ v_w1, const float* __restrict__ n_w1,
    const float* __restrict__ n_w2, const float* __restrict__ ic_wef,
    u16* __restrict__ W) {
  const int m = blockIdx.x;
  if (m == 16) {
    for (int e = threadIdx.x; e < 2048; e += blockDim.x) {
      const int n = e >> 5, k = e & 31;
      W[16 * 4096 + e] = (k < 12) ? f2bf(ic_wef[k * 64 + n]) : (u16)0;
    }
    return;
  }
  const float* src;
  switch (m) {
    case 0: src = br_w1; break;
    case 1: src = br_w1 + 4096; break;
    case 2: src = br_w1 + 8192; break;
    case 3: src = br_w2; break;
    case 4: src = br_w2 + 4096; break;
    case 5: src = br_w2 + 8192; break;
    case 6: src = out_w; break;
    case 7: src = e_w1; break;
    case 8: src = e_w1 + 64 * 64; break;
    case 9: src = e_w1 + 129 * 64; break;
    case 10: src = e_w2; break;
    case 11: src = c_w1; break;
    case 12: src = v_w1; break;
    case 13: src = n_w1; break;
    case 14: src = n_w1 + 64 * 64; break;
    default: src = n_w2; break;
  }
  u16* dst = W + m * 4096;
  for (int e = threadIdx.x; e < 4096; e += blockDim.x) {
    const int n = e >> 6, k = e & 63;
    dst[e] = f2bf(src[k * 64 + n]);
  }
}

__global__ __launch_bounds__(64 * WPB, 2) void egcl_mfma(
    const float* __restrict__ gh, const float* __restrict__ gcoord,
    const float* __restrict__ gvel, const u16* __restrict__ Wg,
    const float* __restrict__ e_w1, const float* __restrict__ e_b1,
    const float* __restrict__ e_b2,
    const float* __restrict__ n_b1, const float* __restrict__ n_b2,
    const float* __restrict__ c_b1, const float* __restrict__ c_w2,
    const float* __restrict__ v_b1, const float* __restrict__ v_w2,
    const float* __restrict__ v_b2,
    const float* __restrict__ ic_pat,
    const float* __restrict__ br_b1, const float* __restrict__ br_b2,
    const float* __restrict__ out_b,
    float* __restrict__ hout, float* __restrict__ cout, int B) {
  // per wave: KA@0 KB@1600 TA@3200 TB@4800 UA@6400 UB@8000 (9600 u16 = 19200B)
  __shared__ __align__(16) u16 arena[WPB][9600];

  const int t = threadIdx.x & 63;
  const int wv = threadIdx.x >> 6;
  const int gA = (blockIdx.x * WPB + wv) * 2;
  if (gA >= B) return;
  int gB = gA + 1;
  if (gB >= B) gB = gA;  // duplicate work, identical writes: benign

  u16* AR = arena[wv];
  u16* KA = AR;           u16* KB = AR + 1600;
  u16* TA = AR + 3200;    u16* TB = AR + 4800;
  u16* UA = AR + 6400;    u16* UB = AR + 8000;
  u16* EFa = TA;  // EF staging in T buffers pre-first-use
  u16* EFb = TB;
  const int c15 = t & 15, q = t >> 4, q8 = q << 3;
  u32 pfa = 0;
#define WT(m) (Wg + (m) * 4096)

  // ---------------- prologue ----------------
  // stacked H A-frags in registers: rows 0-4 = gA nodes, 8-12 = gB nodes
  short8 hA0, hA1;
  {
    int nd = c15 & 7;
    nd = nd > 4 ? 4 : nd;
    const int gg = (c15 & 8) ? gB : gA;
    const float* hp = gh + (size_t)(gg * 5 + nd) * HD + q8;
    const float4 f0 = *reinterpret_cast<const float4*>(hp);
    const float4 f1 = *reinterpret_cast<const float4*>(hp + 4);
    const float4 f2 = *reinterpret_cast<const float4*>(hp + 32);
    const float4 f3 = *reinterpret_cast<const float4*>(hp + 36);
    union { u32 w[4]; short8 s; } u0, u1;
    u0.w[0] = pk2(f0.x, f0.y); u0.w[1] = pk2(f0.z, f0.w);
    u0.w[2] = pk2(f1.x, f1.y); u0.w[3] = pk2(f1.z, f1.w);
    u1.w[0] = pk2(f2.x, f2.y); u1.w[1] = pk2(f2.z, f2.w);
    u1.w[2] = pk2(f3.x, f3.y); u1.w[3] = pk2(f3.z, f3.w);
    hA0 = u0.s;
    hA1 = u1.s;
  }

  // scvreg lanes: 0-14 coordA, 16-30 velA, 32-46 coordB, 48-62 velB
  float scvreg = 0.0f;
  if (t < 15) scvreg = gcoord[gA * 15 + t];
  else if (t >= 16 && t < 31) scvreg = gvel[gA * 15 + (t - 16)];
  else if (t >= 32 && t < 47) scvreg = gcoord[gB * 15 + (t - 32)];
  else if (t >= 48 && t < 63) scvreg = gvel[gB * 15 + (t - 48)];

  // zero EF cols 12..31 for both graphs
#pragma unroll
  for (int z = 0; z < 8; ++z) {
    const int e = t + z * 64;
    if (e < 500) {
      const int gsel = e >= 250;
      const int ee = e - gsel * 250;
      const int row = ee / 10, cc = 12 + (ee % 10) * 2;
      *reinterpret_cast<u32*>((gsel ? EFb : EFa) + row * 32 + cc) = 0u;
    }
  }

  // RBF: lanes 0-24 = graph A tuples, lanes 32-56 = graph B tuples
  float sqcc = 0.0f;
  {
    const int lb = (t >= 32) ? 32 : 0;
    const int tt = t - lb;
    if (tt < 25) {
      u16* EF = lb ? EFb : EFa;
      const int ti = tt / 5, tj = tt % 5;
      const float cix = __shfl(scvreg, lb + ti * 3 + 0, 64), ciy = __shfl(scvreg, lb + ti * 3 + 1, 64), ciz = __shfl(scvreg, lb + ti * 3 + 2, 64);
      const float cjx = __shfl(scvreg, lb + tj * 3 + 0, 64), cjy = __shfl(scvreg, lb + tj * 3 + 1, 64), cjz = __shfl(scvreg, lb + tj * 3 + 2, 64);
      const float vix = __shfl(scvreg, lb + 16 + ti * 3 + 0, 64), viy = __shfl(scvreg, lb + 16 + ti * 3 + 1, 64), viz = __shfl(scvreg, lb + 16 + ti * 3 + 2, 64);
      const float vjx = __shfl(scvreg, lb + 16 + tj * 3 + 0, 64), vjy = __shfl(scvreg, lb + 16 + tj * 3 + 1, 64), vjz = __shfl(scvreg, lb + 16 + tj * 3 + 2, 64);
      {
        const float dx = cix - cjx, dy = ciy - cjy, dz = ciz - cjz;
        sqcc = dx * dx + dy * dy + dz * dz;
      }
      auto sd = [](float sq) { return (sq > 0.0f) ? sqrtf(sq) : 0.0f; };
      float sq2;
      const float dcc = sd(sqcc);
      {
        const float dx = vix - vjx, dy = viy - vjy, dz = viz - vjz;
        sq2 = dx * dx + dy * dy + dz * dz;
      }
      const float dvv = sd(sq2);
      {
        const float dx = cix - vjx, dy = ciy - vjy, dz = ciz - vjz;
        sq2 = dx * dx + dy * dy + dz * dz;
      }
      const float dcv = sd(sq2);
      {
        const float dx = cjx - vix, dy = cjy - viy, dz = cjz - viz;
        sq2 = dx * dx + dy * dy + dz * dz;
      }
      const float dvc = sd(sq2);
      auto rbf3 = [&](float d, int base) {
        const float cut = (d <= 10.0f) ? (0.5f * (cosf(d * 0.31415926535897931f) + 1.0f)) : 0.0f;
        const float e = expf(-0.5f * d);
        const float u0 = e - 4.5399929762484854e-05f;
        const float u1 = e - 0.50002270f;
        const float u2 = e - 1.0f;
        const float BETA = 2.2502043f;
        EF[tt * 32 + base + 0] = f2bf((cut * expf(-BETA * u0 * u0) - 0.05f) * (1.0f / 0.15f));
        EF[tt * 32 + base + 1] = f2bf((cut * expf(-BETA * u1 * u1) - 0.05f) * (1.0f / 0.15f));
        EF[tt * 32 + base + 2] = f2bf((cut * expf(-BETA * u2 * u2) - 0.05f) * (1.0f / 0.15f));
      };
      rbf3(dcc, 0);
      rbf3(dvv, 3);
      rbf3(dcv, 6);
      rbf3(dvc, 9);
    }
  }
  fence();

  // ---------------- kemb (both graphs) -> KA/KB ----------------
  {
    const u32 pfv = reinterpret_cast<const u32*>(WT(1))[t * 32];
    short8 aE[4];
#pragma unroll
    for (int gsel = 0; gsel < 2; ++gsel) {
      const u16* EF = gsel ? EFb : EFa;
#pragma unroll
      for (int mt = 0; mt < 2; ++mt) {
        int row = mt * 16 + c15;
        row = row > 24 ? 24 : row;
        aE[gsel * 2 + mt] = *reinterpret_cast<const short8*>(EF + row * 32 + q8);
      }
    }
    const u16* WTp = Wg + 16 * 4096;
#pragma unroll
    for (int nh = 0; nh < 2; ++nh) {
      f32x4 acc[4][2];
#pragma unroll
      for (int mt = 0; mt < 4; ++mt)
#pragma unroll
        for (int n2 = 0; n2 < 2; ++n2) acc[mt][n2] = (f32x4){0.f, 0.f, 0.f, 0.f};
      short8 b[2];
#pragma unroll
      for (int n2 = 0; n2 < 2; ++n2)
        b[n2] = *reinterpret_cast<const short8*>(WTp + ((nh * 2 + n2) * 16 + c15) * 32 + q8);
#pragma unroll
      for (int mt = 0; mt < 4; ++mt)
#pragma unroll
        for (int n2 = 0; n2 < 2; ++n2)
          acc[mt][n2] = __builtin_amdgcn_mfma_f32_16x16x32_bf16(aE[mt], b[n2], acc[mt][n2], 0, 0, 0);
#pragma unroll
      for (int n2 = 0; n2 < 2; ++n2) {
        const int col = (nh * 2 + n2) * 16 + c15;
        const float p1 = ic_pat[64 + col], p2 = ic_pat[128 + col];
#pragma unroll
        for (int mt = 0; mt < 4; ++mt) {
          u16* K_ = (mt < 2) ? KA : KB;
          const int r0 = (mt & 1) * 16 + q * 4;
          const int bix = uswz(r0, col);
#pragma unroll
          for (int i = 0; i < 4; ++i) {
            const int row = r0 + i;
            if (row < 25) {
              const bool diag = (row % 6) == 0;
              K_[bix + i * 64] = f2bf(acc[mt][n2][i] * (diag ? p2 : p1));
            }
          }
        }
      }
    }
    pfa ^= pfv;
  }
  fence();

  float svc[4][4];

  // ---------------- branch MLPs ----------------
  run_phase2<2, 24, 2>(KA, KB, TA, TB, nullptr, nullptr, WT(1), br_b1 + 64, WT(4), pfa, t); fence();
  run_phase2<2, 24, 2>(TA, TB, UA, UB, nullptr, nullptr, WT(4), br_b2 + 64, WT(2), pfa, t); fence();
  run_phase2<2, 24, 2>(KA, KB, TA, TB, nullptr, nullptr, WT(2), br_b1 + 128, WT(5), pfa, t); fence();
  run_phase2<2, 24, 2>(TA, TB, TA, TB, nullptr, nullptr, WT(5), br_b2 + 128, WT(0), pfa, t); fence();

  // ---------------- einsum (both graphs unrolled): mult -> U ----------------
  {
    float mu[2][25];
#pragma unroll
    for (int gsel = 0; gsel < 2; ++gsel)
#pragma unroll
      for (int p = 0; p < 25; ++p) mu[gsel][p] = 0.0f;
#pragma unroll
    for (int j = 0; j < 5; ++j) {
#pragma unroll
      for (int gsel = 0; gsel < 2; ++gsel) {
        const u16* Tg = gsel ? TB : TA;
        const u16* Ug = gsel ? UB : UA;
        float k1r[5], k0c[5];
#pragma unroll
        for (int k = 0; k < 5; ++k) k1r[k] = bf2f(Tg[uswz(j * 5 + k, t)]);
#pragma unroll
        for (int i = 0; i < 5; ++i) k0c[i] = bf2f(Ug[uswz(i * 5 + j, t)]);
#pragma unroll
        for (int i = 0; i < 5; ++i)
#pragma unroll
          for (int k = 0; k < 5; ++k)
            mu[gsel][i * 5 + k] = fmaf(k0c[i], k1r[k], mu[gsel][i * 5 + k]);
      }
    }
    fence();  // all T/U reads returned before U overwrite
#pragma unroll
    for (int p = 0; p < 25; ++p) {
      UA[uswz(p, t)] = f2bf(mu[0][p]);
      UB[uswz(p, t)] = f2bf(mu[1][p]);
    }
  }
  fence();

  run_phase2<2, 24, 2>(KA, KB, TA, TB, nullptr, nullptr, WT(0), br_b1, WT(3), pfa, t); fence();
  run_phase2<2, 24, 3>(TA, TB, TA, TB, UA, UB, WT(3), br_b2, WT(6), pfa, t); fence();
  run_phase2<2, 24, 4>(TA, TB, KA, KB, nullptr, nullptr, WT(6), out_b, WT(9), pfa, t); fence();
  run_phase2<2, 24, 1>(KA, KB, TA, TB, nullptr, nullptr, WT(9), nullptr, WT(7), pfa, t); fence();

  // ------ stacked H-phase: accA -> U r0-4, accB -> U r8-12, VRED -----------
  float svv[4];
  {
    const u32 pfv = reinterpret_cast<const u32*>(WT(8))[t * 32];
    float s[4] = {0.f, 0.f, 0.f, 0.f};
#pragma unroll
    for (int nh = 0; nh < 2; ++nh) {
      f32x4 aA[1][2], aB[1][2], aV[1][2];
#pragma unroll
      for (int n2 = 0; n2 < 2; ++n2) {
        const float bv = v_b1[(nh * 2 + n2) * 16 + c15];
        aA[0][n2] = (f32x4){0.f, 0.f, 0.f, 0.f};
        aB[0][n2] = (f32x4){0.f, 0.f, 0.f, 0.f};
        aV[0][n2] = (f32x4){bv, bv, bv, bv};
      }
      mmh<1>(&hA0, &hA1, WT(7), aA, t, nh);
      mmh<1>(&hA0, &hA1, WT(8), aB, t, nh);
      mmh<1>(&hA0, &hA1, WT(12), aV, t, nh);
#pragma unroll
      for (int n2 = 0; n2 < 2; ++n2) {
        const int col = (nh * 2 + n2) * 16 + c15;
        const float w2v = v_w2[col];
#pragma unroll
        for (int i = 0; i < 4; ++i) {
          const int r = q * 4 + i;
          if (r < 5) {  // graph A rows
            UA[uswz(r, col)] = f2bf(aA[0][n2][i]);
            UA[uswz(r + 8, col)] = f2bf(aB[0][n2][i]);
          } else if (r >= 8 && r < 13) {  // graph B rows
            UB[uswz(r - 8, col)] = f2bf(aA[0][n2][i]);
            UB[uswz(r, col)] = f2bf(aB[0][n2][i]);
          }
          s[i] += fmaxf(aV[0][n2][i], 0.0f) * w2v;
        }
      }
    }
#pragma unroll
    for (int i = 0; i < 4; ++i) {
      float ss = s[i];
      ss += __shfl_xor(ss, 1, 64);
      ss += __shfl_xor(ss, 2, 64);
      ss += __shfl_xor(ss, 4, 64);
      ss += __shfl_xor(ss, 8, 64);
      svv[i] = ss;  // stacked: gA node i at row i, gB node i at row 8+i
    }
    pfa ^= pfv;
  }
  fence();

  // ---------------- edge assembly (both graphs unrolled) ----------------
  {
    float ec[2][20];
#pragma unroll
    for (int gsel = 0; gsel < 2; ++gsel) {
      const int lb = gsel * 32;
      const u16* Ug = gsel ? UB : UA;
      const u16* Tg = gsel ? TB : TA;
      float aAc[5], aBc[5];
#pragma unroll
      for (int i = 0; i < 5; ++i) {
        aAc[i] = bf2f(Ug[uswz(i, t)]);
        aBc[i] = bf2f(Ug[uswz(8 + i, t)]);
      }
      const float eb1v = e_b1[t];
      const float wradv = e_w1[128 * HD + t];
#pragma unroll
      for (int p = 0; p < 20; ++p) {
        const int i = p >> 2, jj = p & 3;
        const int j = jj + (jj >= i ? 1 : 0);
        const float radial = rlane(sqcc, lb + i * 5 + j);
        const float cc = bf2f(Tg[uswz(i * 5 + j, t)]);
        ec[gsel][p] = fmaxf(aAc[i] + aBc[j] + radial * wradv + cc + eb1v, 0.0f);
      }
    }
    fence();  // reads returned before T overwrite
#pragma unroll
    for (int p = 0; p < 20; ++p) {
      TA[uswz(p, t)] = f2bf(ec[0][p]);
      TB[uswz(p, t)] = f2bf(ec[1][p]);
    }
  }
  fence();

  run_phase2<2, 24, 2>(TA, TB, UA, UB, nullptr, nullptr, WT(10), e_b2, WT(11), pfa, t); fence();

  // ---------------- nagg (stacked into KA rows 0-4 / 8-12) ----------------
#pragma unroll
  for (int gsel = 0; gsel < 2; ++gsel) {
    const u16* Ug = gsel ? UB : UA;
#pragma unroll
    for (int i = 0; i < 5; ++i) {
      float na = 0.0f;
#pragma unroll
      for (int jj = 0; jj < 4; ++jj) na += bf2f(Ug[uswz(4 * i + jj, t)]);
      KA[uswz(gsel * 8 + i, t)] = f2bf(na);
    }
  }
  fence();

  // ---------------- c-model (CRED, both graphs) ----------------
  {
    const u32 pfv = reinterpret_cast<const u32*>(WT(13))[t * 32];
    short8 a0[4], a1[4];
    loadA<2, 24>(UA, t, a0, a1);
    loadA<2, 24>(UB, t, a0 + 2, a1 + 2);
    float s[4][4];
#pragma unroll
    for (int mt = 0; mt < 4; ++mt)
#pragma unroll
      for (int i = 0; i < 4; ++i) s[mt][i] = 0.0f;
#pragma unroll
    for (int nh = 0; nh < 2; ++nh) {
      f32x4 acc[4][2];
#pragma unroll
      for (int n2 = 0; n2 < 2; ++n2) {
        const float bv = c_b1[(nh * 2 + n2) * 16 + c15];
#pragma unroll
        for (int mt = 0; mt < 4; ++mt) acc[mt][n2] = (f32x4){bv, bv, bv, bv};
      }
      mmh<4>(a0, a1, WT(11), acc, t, nh);
#pragma unroll
      for (int n2 = 0; n2 < 2; ++n2) {
        const int col = (nh * 2 + n2) * 16 + c15;
        const float w2v = c_w2[col];
#pragma unroll
        for (int mt = 0; mt < 4; ++mt)
#pragma unroll
          for (int i = 0; i < 4; ++i)
            s[mt][i] += fmaxf(acc[mt][n2][i], 0.0f) * w2v;
      }
    }
#pragma unroll
    for (int mt = 0; mt < 4; ++mt)
#pragma unroll
      for (int i = 0; i < 4; ++i) {
        float ss = s[mt][i];
        ss += __shfl_xor(ss, 1, 64);
        ss += __shfl_xor(ss, 2, 64);
        ss += __shfl_xor(ss, 4, 64);
        ss += __shfl_xor(ss, 8, 64);
        svc[mt][i] = ss;
      }
    pfa ^= pfv;
  }

  // ---------------- coord output (both graphs, VALU only) ----------------
  {
    const float vb2 = v_b2[0];
    float coutreg = 0.0f;
#pragma unroll
    for (int gsel = 0; gsel < 2; ++gsel) {
      const int lb = gsel * 32;
#pragma unroll
      for (int i = 0; i < 5; ++i) {
        const int rr = gsel * 8 + i;  // stacked VRED row
        const float vmi = rlane(svv[rr & 3], (rr >> 2) << 4) + vb2;
#pragma unroll
        for (int dd = 0; dd < 3; ++dd) {
          const float ci = rlane(scvreg, lb + i * 3 + dd);
          float s = 0.0f;
#pragma unroll
          for (int jj = 0; jj < 4; ++jj) {
            const int j = jj + (jj >= i ? 1 : 0);
            const int p = i * 4 + jj;
            const float cmp = rlane(svc[gsel * 2 + (p >> 4)][p & 3], ((p & 15) >> 2) << 4);
            float tr = (ci - rlane(scvreg, lb + j * 3 + dd)) * cmp;
            tr = fminf(fmaxf(tr, -100.0f), 100.0f);
            s += tr;
          }
          const float val = ci + 0.25f * s + rlane(scvreg, lb + 16 + i * 3 + dd) * vmi;
          if (t == lb + i * 3 + dd) coutreg = val;
        }
      }
    }
    if (t < 15) cout[gA * 15 + t] = coutreg;
    else if (t >= 32 && t < 47) cout[gB * 15 + (t - 32)] = coutreg;
  }

  // ---------------- node model L1 (stacked) -> TA rows 0-4 / 8-12 ----------
  {
    const u32 pfv = reinterpret_cast<const u32*>(WT(15))[t * 32];
    short8 a0k[1], a1k[1];
    loadA<1, 15>(KA, t, a0k, a1k);  // stacked nagg (garbage rows harmless)
#pragma unroll
    for (int nh = 0; nh < 2; ++nh) {
      f32x4 acc[1][2];
#pragma unroll
      for (int n2 = 0; n2 < 2; ++n2) {
        const float nb = n_b1[(nh * 2 + n2) * 16 + c15];
        acc[0][n2] = (f32x4){nb, nb, nb, nb};
      }
      mmh<1>(&hA0, &hA1, WT(13), acc, t, nh);
      mmh<1>(a0k, a1k, WT(14), acc, t, nh);
#pragma unroll
      for (int n2 = 0; n2 < 2; ++n2) {
        const int col = (nh * 2 + n2) * 16 + c15;
#pragma unroll
        for (int i = 0; i < 4; ++i) {
          const int r = q * 4 + i;
          if (r < 5 || (r >= 8 && r < 13))
            TA[uswz(r, col)] = f2bf(fmaxf(acc[0][n2][i], 0.0f));
        }
      }
    }
    pfa ^= pfv;
  }
  fence();

  // ---------------- node model L2 (stacked) + residual -> hout -------------
  {
    short8 a0[1], a1[1];
    loadA<1, 15>(TA, t, a0, a1);
#pragma unroll
    for (int nh = 0; nh < 2; ++nh) {
      f32x4 acc[1][2];
#pragma unroll
      for (int n2 = 0; n2 < 2; ++n2) {
        const float nb = n_b2[(nh * 2 + n2) * 16 + c15];
        acc[0][n2] = (f32x4){nb, nb, nb, nb};
      }
      mmh<1>(a0, a1, WT(15), acc, t, nh);
#pragma unroll
      for (int n2 = 0; n2 < 2; ++n2) {
        const int col = (nh * 2 + n2) * 16 + c15;
#pragma unroll
        for (int i = 0; i < 4; ++i) {
          const int r = q * 4 + i;
          if (r < 5) {
            const size_t ix = (size_t)(gA * 5 + r) * HD + col;
            hout[ix] = gh[ix] + acc[0][n2][i];
          } else if (r >= 8 && r < 13) {
            const size_t ix = (size_t)(gB * 5 + (r - 8)) * HD + col;
            hout[ix] = gh[ix] + acc[0][n2][i];
          }
        }
      }
    }
  }

  if (B == -7) cout[1] = __uint_as_float(pfa);  // keep prefetch loads live
#undef WT
}

extern "C" void kernel_launch(void* const* d_in, const int* in_sizes, int n_in,
                              void* d_out, int out_size, void* d_ws, size_t ws_size,
                              hipStream_t stream) {
  if (n_in < 27) return;
  const float* gh    = (const float*)d_in[0];
  const float* coord = (const float*)d_in[1];
  const float* vel   = (const float*)d_in[2];
  const float* e_w1 = (const float*)d_in[4];
  const float* e_b1 = (const float*)d_in[5];
  const float* e_w2 = (const float*)d_in[6];
  const float* e_b2 = (const float*)d_in[7];
  const float* n_w1 = (const float*)d_in[8];
  const float* n_b1 = (const float*)d_in[9];
  const float* n_w2 = (const float*)d_in[10];
  const float* n_b2 = (const float*)d_in[11];
  const float* c_w1 = (const float*)d_in[12];
  const float* c_b1 = (const float*)d_in[13];
  const float* c_w2 = (const float*)d_in[14];
  const float* v_w1 = (const float*)d_in[15];
  const float* v_b1 = (const float*)d_in[16];
  const float* v_w2 = (const float*)d_in[17];
  const float* v_b2 = (const float*)d_in[18];
  const float* ic_wef = (const float*)d_in[19];
  const float* ic_pat = (const float*)d_in[20];
  const float* br_w1 = (const float*)d_in[21];
  const float* br_b1 = (const float*)d_in[22];
  const float* br_w2 = (const float*)d_in[23];
  const float* br_b2 = (const float*)d_in[24];
  const float* out_w = (const float*)d_in[25];
  const float* out_b = (const float*)d_in[26];

  const int N = in_sizes[0] / HD;  // 100000
  const int B = N / 5;             // 20000 graphs
  float* hout = (float*)d_out;
  float* cout = (float*)d_out + (size_t)N * HD;
  u16* W = (u16*)d_ws;  // 16*4096 + 2048 u16 = 135168 B

  prepack<<<17, 256, 0, stream>>>(br_w1, br_w2, out_w, e_w1, e_w2, c_w1, v_w1,
                                  n_w1, n_w2, ic_wef, W);

  const int gpb = WPB * 2;  // graphs per block
  const int blocks = (B + gpb - 1) / gpb;
  egcl_mfma<<<blocks, 64 * WPB, 0, stream>>>(
      gh, coord, vel, W, e_w1, e_b1, e_b2, n_b1, n_b2, c_b1, c_w2, v_b1, v_w2,
      v_b2, ic_pat, br_b1, br_b2, out_b, hout, cout, B);
}

// Round 13
// 237.410 us; speedup vs baseline: 1.3671x; 1.0360x over previous
//
#include <hip/hip_runtime.h>
#include <math.h>

#define HD 64
#define WPB 2  // waves per block; each wave handles TWO graphs

typedef unsigned short u16;
typedef unsigned int u32;
typedef __attribute__((ext_vector_type(8))) short short8;
typedef __attribute__((ext_vector_type(4))) float f32x4;

__device__ __forceinline__ u16 f2bf(float f) {
  u32 r;
  asm("v_cvt_pk_bf16_f32 %0, %1, %2" : "=v"(r) : "v"(f), "v"(f));
  return (u16)r;
}
__device__ __forceinline__ u32 pk2(float lo, float hi) {
  u32 r;
  asm("v_cvt_pk_bf16_f32 %0, %1, %2" : "=v"(r) : "v"(lo), "v"(hi));
  return r;
}
__device__ __forceinline__ float bf2f(u16 x) {
  return __uint_as_float(((u32)x) << 16);
}
// Quadrant swizzle (validated R10): XOR row bits 2-3 into col bits 4-5.
__device__ __forceinline__ int uswz(int row, int col) {
  return (row << 6) | (col ^ (((row >> 2) & 3) << 4));
}
__device__ __forceinline__ float rlane(float v, int l) {
  return __uint_as_float(__builtin_amdgcn_readlane(__float_as_uint(v), l));
}
// Wave-local LDS fence (R9 race post-mortem): drains DS ops at buffer-reuse
// boundaries. In-window in-place matmuls are safe WITHOUT fences (write data
// depends on the reads via MFMA); only cross-phase reuse needs this.
__device__ __forceinline__ void fence() {
  asm volatile("s_waitcnt lgkmcnt(0)" ::: "memory");
}

template <int MT, int RMAX>
__device__ __forceinline__ void loadA(const u16* A_, int t, short8* a0, short8* a1) {
  const int q8 = (t >> 4) << 3;
#pragma unroll
  for (int mt = 0; mt < MT; ++mt) {
    int row = mt * 16 + (t & 15);
    row = row > RMAX ? RMAX : row;
    const int idx = uswz(row, q8);
    a0[mt] = *reinterpret_cast<const short8*>(A_ + idx);
    a1[mt] = *reinterpret_cast<const short8*>(A_ + (idx ^ 32));
  }
}

template <int MTT>
__device__ __forceinline__ void mmh(const short8* a0, const short8* a1,
                                    const u16* __restrict__ WT, f32x4 (*acc)[2],
                                    int t, int nh) {
  const int c15 = t & 15;
  const int q8 = (t >> 4) << 3;
  short8 b[2][2];
#pragma unroll
  for (int n2 = 0; n2 < 2; ++n2) {
    const int nt = nh * 2 + n2;
#pragma unroll
    for (int s = 0; s < 2; ++s)
      b[n2][s] = *reinterpret_cast<const short8*>(WT + (nt * 16 + c15) * 64 + s * 32 + q8);
  }
#pragma unroll
  for (int mt = 0; mt < MTT; ++mt) {
#pragma unroll
    for (int n2 = 0; n2 < 2; ++n2)
      acc[mt][n2] = __builtin_amdgcn_mfma_f32_16x16x32_bf16(a0[mt], b[n2][0], acc[mt][n2], 0, 0, 0);
#pragma unroll
    for (int n2 = 0; n2 < 2; ++n2)
      acc[mt][n2] = __builtin_amdgcn_mfma_f32_16x16x32_bf16(a1[mt], b[n2][1], acc[mt][n2], 0, 0, 0);
  }
}

// two-graph single-stream phase. EPI: 1=store, 2=relu, 3=relu*M, 4=relu + D.
template <int MT, int RMAX, int EPI>
__device__ __forceinline__ void run_phase2(const u16* AA, const u16* AB,
                                           u16* DA, u16* DB,
                                           const u16* MA, const u16* MB,
                                           const u16* __restrict__ WT,
                                           const float* __restrict__ bias,
                                           int t, int rowoff = 0) {
  const int c15 = t & 15, q = t >> 4;
  constexpr int rowlim = (MT == 2) ? 25 : 5;
  short8 a0[2 * MT], a1[2 * MT];
  loadA<MT, RMAX>(AA, t, a0, a1);
  loadA<MT, RMAX>(AB, t, a0 + MT, a1 + MT);
#pragma unroll
  for (int nh = 0; nh < 2; ++nh) {
    f32x4 acc[2 * MT][2];
#pragma unroll
    for (int n2 = 0; n2 < 2; ++n2) {
      const int col = (nh * 2 + n2) * 16 + c15;
      const float bb = bias ? bias[col] : 0.0f;
#pragma unroll
      for (int mt = 0; mt < 2 * MT; ++mt) acc[mt][n2] = (f32x4){bb, bb, bb, bb};
    }
    mmh<2 * MT>(a0, a1, WT, acc, t, nh);
#pragma unroll
    for (int n2 = 0; n2 < 2; ++n2) {
      const int col = (nh * 2 + n2) * 16 + c15;
#pragma unroll
      for (int mt = 0; mt < 2 * MT; ++mt) {
        u16* D_ = (mt < MT) ? DA : DB;
        const u16* M_ = (mt < MT) ? MA : MB;
        const int r0 = (mt % MT) * 16 + q * 4;
        const int bix = uswz(r0 + rowoff, col);
#pragma unroll
        for (int i = 0; i < 4; ++i) {
          if (r0 + i < rowlim) {
            const int ix = bix + i * 64;
            float v = acc[mt][n2][i];
            if (EPI >= 2) v = fmaxf(v, 0.0f);
            if (EPI == 3) v *= bf2f(M_[ix]);
            if (EPI == 4) v += bf2f(D_[ix]);
            D_[ix] = f2bf(v);
          }
        }
      }
    }
  }
}

// ---- pre-pass: pack weights to bf16 transposed [n][k] ----
__global__ __launch_bounds__(256) void prepack(
    const float* __restrict__ br_w1, const float* __restrict__ br_w2,
    const float* __restrict__ out_w, const float* __restrict__ e_w1,
    const float* __restrict__ e_w2, const float* __restrict__ c_w1,
    const float* __restrict__ v_w1, const float* __restrict__ n_w1,
    const float* __restrict__ n_w2, const float* __restrict__ ic_wef,
    u16* __restrict__ W) {
  const int m = blockIdx.x;
  if (m == 16) {
    for (int e = threadIdx.x; e < 2048; e += blockDim.x) {
      const int n = e >> 5, k = e & 31;
      W[16 * 4096 + e] = (k < 12) ? f2bf(ic_wef[k * 64 + n]) : (u16)0;
    }
    return;
  }
  const float* src;
  switch (m) {
    case 0: src = br_w1; break;
    case 1: src = br_w1 + 4096; break;
    case 2: src = br_w1 + 8192; break;
    case 3: src = br_w2; break;
    case 4: src = br_w2 + 4096; break;
    case 5: src = br_w2 + 8192; break;
    case 6: src = out_w; break;
    case 7: src = e_w1; break;
    case 8: src = e_w1 + 64 * 64; break;
    case 9: src = e_w1 + 129 * 64; break;
    case 10: src = e_w2; break;
    case 11: src = c_w1; break;
    case 12: src = v_w1; break;
    case 13: src = n_w1; break;
    case 14: src = n_w1 + 64 * 64; break;
    default: src = n_w2; break;
  }
  u16* dst = W + m * 4096;
  for (int e = threadIdx.x; e < 4096; e += blockDim.x) {
    const int n = e >> 6, k = e & 63;
    dst[e] = f2bf(src[k * 64 + n]);
  }
}

__global__ __launch_bounds__(64 * WPB, 2) void egcl_mfma(
    const float* __restrict__ gh, const float* __restrict__ gcoord,
    const float* __restrict__ gvel, const u16* __restrict__ Wg,
    const float* __restrict__ e_w1, const float* __restrict__ e_b1,
    const float* __restrict__ e_b2,
    const float* __restrict__ n_b1, const float* __restrict__ n_b2,
    const float* __restrict__ c_b1, const float* __restrict__ c_w2,
    const float* __restrict__ v_b1, const float* __restrict__ v_w2,
    const float* __restrict__ v_b2,
    const float* __restrict__ ic_pat,
    const float* __restrict__ br_b1, const float* __restrict__ br_b2,
    const float* __restrict__ out_b,
    float* __restrict__ hout, float* __restrict__ cout, int B) {
  // per wave: KA@0 KB@1600 TA@3200 TB@4800 UA@6400 UB@8000 (9600 u16 = 19200B)
  __shared__ __align__(16) u16 arena[WPB][9600];

  const int t = threadIdx.x & 63;
  const int wv = threadIdx.x >> 6;
  const int gA = (blockIdx.x * WPB + wv) * 2;
  if (gA >= B) return;
  int gB = gA + 1;
  if (gB >= B) gB = gA;  // duplicate work, identical writes: benign

  u16* AR = arena[wv];
  u16* KA = AR;           u16* KB = AR + 1600;
  u16* TA = AR + 3200;    u16* TB = AR + 4800;
  u16* UA = AR + 6400;    u16* UB = AR + 8000;
  u16* EFa = TA;  // EF staging in T buffers pre-first-use
  u16* EFb = TB;
  const int c15 = t & 15, q = t >> 4, q8 = q << 3;
#define WT(m) (Wg + (m) * 4096)

  // ---------------- prologue ----------------
  // stacked H A-frags in registers: rows 0-4 = gA nodes, 8-12 = gB nodes
  short8 hA0, hA1;
  {
    int nd = c15 & 7;
    nd = nd > 4 ? 4 : nd;
    const int gg = (c15 & 8) ? gB : gA;
    const float* hp = gh + (size_t)(gg * 5 + nd) * HD + q8;
    const float4 f0 = *reinterpret_cast<const float4*>(hp);
    const float4 f1 = *reinterpret_cast<const float4*>(hp + 4);
    const float4 f2 = *reinterpret_cast<const float4*>(hp + 32);
    const float4 f3 = *reinterpret_cast<const float4*>(hp + 36);
    union { u32 w[4]; short8 s; } u0, u1;
    u0.w[0] = pk2(f0.x, f0.y); u0.w[1] = pk2(f0.z, f0.w);
    u0.w[2] = pk2(f1.x, f1.y); u0.w[3] = pk2(f1.z, f1.w);
    u1.w[0] = pk2(f2.x, f2.y); u1.w[1] = pk2(f2.z, f2.w);
    u1.w[2] = pk2(f3.x, f3.y); u1.w[3] = pk2(f3.z, f3.w);
    hA0 = u0.s;
    hA1 = u1.s;
  }

  // scvreg lanes: 0-14 coordA, 16-30 velA, 32-46 coordB, 48-62 velB
  float scvreg = 0.0f;
  if (t < 15) scvreg = gcoord[gA * 15 + t];
  else if (t >= 16 && t < 31) scvreg = gvel[gA * 15 + (t - 16)];
  else if (t >= 32 && t < 47) scvreg = gcoord[gB * 15 + (t - 32)];
  else if (t >= 48 && t < 63) scvreg = gvel[gB * 15 + (t - 48)];

  // zero EF cols 12..31 for both graphs
#pragma unroll
  for (int z = 0; z < 8; ++z) {
    const int e = t + z * 64;
    if (e < 500) {
      const int gsel = e >= 250;
      const int ee = e - gsel * 250;
      const int row = ee / 10, cc = 12 + (ee % 10) * 2;
      *reinterpret_cast<u32*>((gsel ? EFb : EFa) + row * 32 + cc) = 0u;
    }
  }

  // RBF: lanes 0-24 = graph A tuples, lanes 32-56 = graph B tuples
  float sqcc = 0.0f;
  {
    const int lb = (t >= 32) ? 32 : 0;
    const int tt = t - lb;
    if (tt < 25) {
      u16* EF = lb ? EFb : EFa;
      const int ti = tt / 5, tj = tt % 5;
      const float cix = __shfl(scvreg, lb + ti * 3 + 0, 64), ciy = __shfl(scvreg, lb + ti * 3 + 1, 64), ciz = __shfl(scvreg, lb + ti * 3 + 2, 64);
      const float cjx = __shfl(scvreg, lb + tj * 3 + 0, 64), cjy = __shfl(scvreg, lb + tj * 3 + 1, 64), cjz = __shfl(scvreg, lb + tj * 3 + 2, 64);
      const float vix = __shfl(scvreg, lb + 16 + ti * 3 + 0, 64), viy = __shfl(scvreg, lb + 16 + ti * 3 + 1, 64), viz = __shfl(scvreg, lb + 16 + ti * 3 + 2, 64);
      const float vjx = __shfl(scvreg, lb + 16 + tj * 3 + 0, 64), vjy = __shfl(scvreg, lb + 16 + tj * 3 + 1, 64), vjz = __shfl(scvreg, lb + 16 + tj * 3 + 2, 64);
      {
        const float dx = cix - cjx, dy = ciy - cjy, dz = ciz - cjz;
        sqcc = dx * dx + dy * dy + dz * dz;
      }
      auto sd = [](float sq) { return (sq > 0.0f) ? sqrtf(sq) : 0.0f; };
      float sq2;
      const float dcc = sd(sqcc);
      {
        const float dx = vix - vjx, dy = viy - vjy, dz = viz - vjz;
        sq2 = dx * dx + dy * dy + dz * dz;
      }
      const float dvv = sd(sq2);
      {
        const float dx = cix - vjx, dy = ciy - vjy, dz = ciz - vjz;
        sq2 = dx * dx + dy * dy + dz * dz;
      }
      const float dcv = sd(sq2);
      {
        const float dx = cjx - vix, dy = cjy - viy, dz = cjz - viz;
        sq2 = dx * dx + dy * dy + dz * dz;
      }
      const float dvc = sd(sq2);
      auto rbf3 = [&](float d, int base) {
        const float cut = (d <= 10.0f) ? (0.5f * (cosf(d * 0.31415926535897931f) + 1.0f)) : 0.0f;
        const float e = expf(-0.5f * d);
        const float u0 = e - 4.5399929762484854e-05f;
        const float u1 = e - 0.50002270f;
        const float u2 = e - 1.0f;
        const float BETA = 2.2502043f;
        EF[tt * 32 + base + 0] = f2bf((cut * expf(-BETA * u0 * u0) - 0.05f) * (1.0f / 0.15f));
        EF[tt * 32 + base + 1] = f2bf((cut * expf(-BETA * u1 * u1) - 0.05f) * (1.0f / 0.15f));
        EF[tt * 32 + base + 2] = f2bf((cut * expf(-BETA * u2 * u2) - 0.05f) * (1.0f / 0.15f));
      };
      rbf3(dcc, 0);
      rbf3(dvv, 3);
      rbf3(dcv, 6);
      rbf3(dvc, 9);
    }
  }
  fence();

  // ---------------- kemb (both graphs) -> KA/KB ----------------
  {
    short8 aE[4];
#pragma unroll
    for (int gsel = 0; gsel < 2; ++gsel) {
      const u16* EF = gsel ? EFb : EFa;
#pragma unroll
      for (int mt = 0; mt < 2; ++mt) {
        int row = mt * 16 + c15;
        row = row > 24 ? 24 : row;
        aE[gsel * 2 + mt] = *reinterpret_cast<const short8*>(EF + row * 32 + q8);
      }
    }
    const u16* WTp = Wg + 16 * 4096;
#pragma unroll
    for (int nh = 0; nh < 2; ++nh) {
      f32x4 acc[4][2];
#pragma unroll
      for (int mt = 0; mt < 4; ++mt)
#pragma unroll
        for (int n2 = 0; n2 < 2; ++n2) acc[mt][n2] = (f32x4){0.f, 0.f, 0.f, 0.f};
      short8 b[2];
#pragma unroll
      for (int n2 = 0; n2 < 2; ++n2)
        b[n2] = *reinterpret_cast<const short8*>(WTp + ((nh * 2 + n2) * 16 + c15) * 32 + q8);
#pragma unroll
      for (int mt = 0; mt < 4; ++mt)
#pragma unroll
        for (int n2 = 0; n2 < 2; ++n2)
          acc[mt][n2] = __builtin_amdgcn_mfma_f32_16x16x32_bf16(aE[mt], b[n2], acc[mt][n2], 0, 0, 0);
#pragma unroll
      for (int n2 = 0; n2 < 2; ++n2) {
        const int col = (nh * 2 + n2) * 16 + c15;
        const float p1 = ic_pat[64 + col], p2 = ic_pat[128 + col];
#pragma unroll
        for (int mt = 0; mt < 4; ++mt) {
          u16* K_ = (mt < 2) ? KA : KB;
          const int r0 = (mt & 1) * 16 + q * 4;
          const int bix = uswz(r0, col);
#pragma unroll
          for (int i = 0; i < 4; ++i) {
            const int row = r0 + i;
            if (row < 25) {
              const bool diag = (row % 6) == 0;
              K_[bix + i * 64] = f2bf(acc[mt][n2][i] * (diag ? p2 : p1));
            }
          }
        }
      }
    }
  }
  fence();

  // -------- Window A: k0L1 (W1) K->T  ||  k1L1 (W2) K->U  (shared A) -------
  {
    short8 a0[4], a1[4];
    loadA<2, 24>(KA, t, a0, a1);
    loadA<2, 24>(KB, t, a0 + 2, a1 + 2);
#pragma unroll
    for (int nh = 0; nh < 2; ++nh) {
      f32x4 ac0[4][2], ac1[4][2];
#pragma unroll
      for (int n2 = 0; n2 < 2; ++n2) {
        const int col = (nh * 2 + n2) * 16 + c15;
        const float b0 = br_b1[64 + col], b1 = br_b1[128 + col];
#pragma unroll
        for (int mt = 0; mt < 4; ++mt) {
          ac0[mt][n2] = (f32x4){b0, b0, b0, b0};
          ac1[mt][n2] = (f32x4){b1, b1, b1, b1};
        }
      }
      mmh<4>(a0, a1, WT(1), ac0, t, nh);
      mmh<4>(a0, a1, WT(2), ac1, t, nh);
#pragma unroll
      for (int n2 = 0; n2 < 2; ++n2) {
        const int col = (nh * 2 + n2) * 16 + c15;
#pragma unroll
        for (int mt = 0; mt < 4; ++mt) {
          u16* T_ = (mt < 2) ? TA : TB;
          u16* U_ = (mt < 2) ? UA : UB;
          const int r0 = (mt & 1) * 16 + q * 4;
          const int bix = uswz(r0, col);
#pragma unroll
          for (int i = 0; i < 4; ++i) {
            if (r0 + i < 25) {
              T_[bix + i * 64] = f2bf(fmaxf(ac0[mt][n2][i], 0.0f));
              U_[bix + i * 64] = f2bf(fmaxf(ac1[mt][n2][i], 0.0f));
            }
          }
        }
      }
    }
  }
  fence();

  // -------- Window B: k0L2 (W4) T->T  ||  k1L2 (W5) U->U  (in-place) -------
  {
    short8 a0[4], a1[4], c0[4], c1[4];
    loadA<2, 24>(TA, t, a0, a1);
    loadA<2, 24>(TB, t, a0 + 2, a1 + 2);
    loadA<2, 24>(UA, t, c0, c1);
    loadA<2, 24>(UB, t, c0 + 2, c1 + 2);
#pragma unroll
    for (int nh = 0; nh < 2; ++nh) {
      f32x4 ac0[4][2], ac1[4][2];
#pragma unroll
      for (int n2 = 0; n2 < 2; ++n2) {
        const int col = (nh * 2 + n2) * 16 + c15;
        const float b0 = br_b2[64 + col], b1 = br_b2[128 + col];
#pragma unroll
        for (int mt = 0; mt < 4; ++mt) {
          ac0[mt][n2] = (f32x4){b0, b0, b0, b0};
          ac1[mt][n2] = (f32x4){b1, b1, b1, b1};
        }
      }
      mmh<4>(a0, a1, WT(4), ac0, t, nh);
      mmh<4>(c0, c1, WT(5), ac1, t, nh);
#pragma unroll
      for (int n2 = 0; n2 < 2; ++n2) {
        const int col = (nh * 2 + n2) * 16 + c15;
#pragma unroll
        for (int mt = 0; mt < 4; ++mt) {
          u16* T_ = (mt < 2) ? TA : TB;
          u16* U_ = (mt < 2) ? UA : UB;
          const int r0 = (mt & 1) * 16 + q * 4;
          const int bix = uswz(r0, col);
#pragma unroll
          for (int i = 0; i < 4; ++i) {
            if (r0 + i < 25) {
              T_[bix + i * 64] = f2bf(fmaxf(ac0[mt][n2][i], 0.0f));
              U_[bix + i * 64] = f2bf(fmaxf(ac1[mt][n2][i], 0.0f));
            }
          }
        }
      }
    }
  }
  fence();

  // ---------------- einsum (both graphs): mult = k0(T) @ k1(U) -> U --------
  {
    float mu[2][25];
#pragma unroll
    for (int gsel = 0; gsel < 2; ++gsel)
#pragma unroll
      for (int p = 0; p < 25; ++p) mu[gsel][p] = 0.0f;
#pragma unroll
    for (int j = 0; j < 5; ++j) {
#pragma unroll
      for (int gsel = 0; gsel < 2; ++gsel) {
        const u16* Tg = gsel ? TB : TA;
        const u16* Ug = gsel ? UB : UA;
        float k1r[5], k0c[5];
#pragma unroll
        for (int k = 0; k < 5; ++k) k1r[k] = bf2f(Ug[uswz(j * 5 + k, t)]);
#pragma unroll
        for (int i = 0; i < 5; ++i) k0c[i] = bf2f(Tg[uswz(i * 5 + j, t)]);
#pragma unroll
        for (int i = 0; i < 5; ++i)
#pragma unroll
          for (int k = 0; k < 5; ++k)
            mu[gsel][i * 5 + k] = fmaf(k0c[i], k1r[k], mu[gsel][i * 5 + k]);
      }
    }
    fence();  // all T/U reads returned before U overwrite
#pragma unroll
    for (int p = 0; p < 25; ++p) {
      UA[uswz(p, t)] = f2bf(mu[0][p]);
      UB[uswz(p, t)] = f2bf(mu[1][p]);
    }
  }
  fence();

  run_phase2<2, 24, 2>(KA, KB, TA, TB, nullptr, nullptr, WT(0), br_b1, t); fence();  // smL1 K->T
  run_phase2<2, 24, 3>(TA, TB, TA, TB, UA, UB, WT(3), br_b2, t); fence();            // z = relu(sm)*mult -> T
  run_phase2<2, 24, 4>(TA, TB, KA, KB, nullptr, nullptr, WT(6), out_b, t); fence();  // residual -> K

  // ------ Window F: accC (W9) K->T || stacked-H (W7,W8->U; W12 VRED) -------
  float svv[4];
  {
    short8 a0[4], a1[4];
    loadA<2, 24>(KA, t, a0, a1);
    loadA<2, 24>(KB, t, a0 + 2, a1 + 2);
    float s[4] = {0.f, 0.f, 0.f, 0.f};
#pragma unroll
    for (int nh = 0; nh < 2; ++nh) {
      f32x4 accC[4][2], aA[1][2], aB[1][2], aV[1][2];
#pragma unroll
      for (int n2 = 0; n2 < 2; ++n2) {
        const float bv = v_b1[(nh * 2 + n2) * 16 + c15];
#pragma unroll
        for (int mt = 0; mt < 4; ++mt) accC[mt][n2] = (f32x4){0.f, 0.f, 0.f, 0.f};
        aA[0][n2] = (f32x4){0.f, 0.f, 0.f, 0.f};
        aB[0][n2] = (f32x4){0.f, 0.f, 0.f, 0.f};
        aV[0][n2] = (f32x4){bv, bv, bv, bv};
      }
      mmh<4>(a0, a1, WT(9), accC, t, nh);
      mmh<1>(&hA0, &hA1, WT(7), aA, t, nh);
      mmh<1>(&hA0, &hA1, WT(8), aB, t, nh);
      mmh<1>(&hA0, &hA1, WT(12), aV, t, nh);
#pragma unroll
      for (int n2 = 0; n2 < 2; ++n2) {
        const int col = (nh * 2 + n2) * 16 + c15;
        const float w2v = v_w2[col];
#pragma unroll
        for (int mt = 0; mt < 4; ++mt) {  // accC -> T (store, no relu)
          u16* T_ = (mt < 2) ? TA : TB;
          const int r0 = (mt & 1) * 16 + q * 4;
          const int bix = uswz(r0, col);
#pragma unroll
          for (int i = 0; i < 4; ++i)
            if (r0 + i < 25) T_[bix + i * 64] = f2bf(accC[mt][n2][i]);
        }
#pragma unroll
        for (int i = 0; i < 4; ++i) {  // stacked accA/accB -> U, VRED partial
          const int r = q * 4 + i;
          if (r < 5) {
            UA[uswz(r, col)] = f2bf(aA[0][n2][i]);
            UA[uswz(r + 8, col)] = f2bf(aB[0][n2][i]);
          } else if (r >= 8 && r < 13) {
            UB[uswz(r - 8, col)] = f2bf(aA[0][n2][i]);
            UB[uswz(r, col)] = f2bf(aB[0][n2][i]);
          }
          s[i] += fmaxf(aV[0][n2][i], 0.0f) * w2v;
        }
      }
    }
#pragma unroll
    for (int i = 0; i < 4; ++i) {
      float ss = s[i];
      ss += __shfl_xor(ss, 1, 64);
      ss += __shfl_xor(ss, 2, 64);
      ss += __shfl_xor(ss, 4, 64);
      ss += __shfl_xor(ss, 8, 64);
      svv[i] = ss;  // stacked: gA node i at row i, gB node i at row 8+i
    }
  }
  fence();

  // ---------------- edge assembly (both graphs) ----------------
  {
    float ec[2][20];
#pragma unroll
    for (int gsel = 0; gsel < 2; ++gsel) {
      const int lb = gsel * 32;
      const u16* Ug = gsel ? UB : UA;
      const u16* Tg = gsel ? TB : TA;
      float aAc[5], aBc[5];
#pragma unroll
      for (int i = 0; i < 5; ++i) {
        aAc[i] = bf2f(Ug[uswz(i, t)]);
        aBc[i] = bf2f(Ug[uswz(8 + i, t)]);
      }
      const float eb1v = e_b1[t];
      const float wradv = e_w1[128 * HD + t];
#pragma unroll
      for (int p = 0; p < 20; ++p) {
        const int i = p >> 2, jj = p & 3;
        const int j = jj + (jj >= i ? 1 : 0);
        const float radial = rlane(sqcc, lb + i * 5 + j);
        const float cc = bf2f(Tg[uswz(i * 5 + j, t)]);
        ec[gsel][p] = fmaxf(aAc[i] + aBc[j] + radial * wradv + cc + eb1v, 0.0f);
      }
    }
    fence();  // reads returned before T overwrite
#pragma unroll
    for (int p = 0; p < 20; ++p) {
      TA[uswz(p, t)] = f2bf(ec[0][p]);
      TB[uswz(p, t)] = f2bf(ec[1][p]);
    }
  }
  fence();

  // ------ Window G: edge_feat (W10) T->U with FUSED nagg -> KA rows --------
  {
    short8 a0[4], a1[4];
    loadA<2, 24>(TA, t, a0, a1);
    loadA<2, 24>(TB, t, a0 + 2, a1 + 2);
#pragma unroll
    for (int nh = 0; nh < 2; ++nh) {
      f32x4 acc[4][2];
#pragma unroll
      for (int n2 = 0; n2 < 2; ++n2) {
        const float bb = e_b2[(nh * 2 + n2) * 16 + c15];
#pragma unroll
        for (int mt = 0; mt < 4; ++mt) acc[mt][n2] = (f32x4){bb, bb, bb, bb};
      }
      mmh<4>(a0, a1, WT(10), acc, t, nh);
#pragma unroll
      for (int n2 = 0; n2 < 2; ++n2) {
        const int col = (nh * 2 + n2) * 16 + c15;
#pragma unroll
        for (int mt = 0; mt < 4; ++mt) {
          u16* U_ = (mt < 2) ? UA : UB;
          const int gsel = mt >> 1;
          const int r0 = (mt & 1) * 16 + q * 4;
          const int bix = uswz(r0, col);
          float na = 0.0f;
#pragma unroll
          for (int i = 0; i < 4; ++i) {
            const float v = fmaxf(acc[mt][n2][i], 0.0f);
            if (r0 + i < 25) U_[bix + i * 64] = f2bf(v);
            na += v;
          }
          // nagg: tile0 -> node q; tile1 (rows 16-19, q==0) -> node 4
          if (!(mt & 1)) {
            KA[uswz(gsel * 8 + q, col)] = f2bf(na);
          } else if (q == 0) {
            KA[uswz(gsel * 8 + 4, col)] = f2bf(na);
          }
        }
      }
    }
  }
  fence();

  // ------ Window CR: CRED (W11) U->svc  ||  nodeL1 (W13 H + W14 Knagg)->T --
  float svc[4][4];
  {
    short8 u0[4], u1[4], k0[1], k1[1];
    loadA<2, 24>(UA, t, u0, u1);
    loadA<2, 24>(UB, t, u0 + 2, u1 + 2);
    loadA<1, 15>(KA, t, k0, k1);  // stacked nagg (garbage rows harmless)
    float s[4][4];
#pragma unroll
    for (int mt = 0; mt < 4; ++mt)
#pragma unroll
      for (int i = 0; i < 4; ++i) s[mt][i] = 0.0f;
#pragma unroll
    for (int nh = 0; nh < 2; ++nh) {
      f32x4 accc[4][2], accn[1][2];
#pragma unroll
      for (int n2 = 0; n2 < 2; ++n2) {
        const int col = (nh * 2 + n2) * 16 + c15;
        const float bv = c_b1[col];
        const float nb = n_b1[col];
#pragma unroll
        for (int mt = 0; mt < 4; ++mt) accc[mt][n2] = (f32x4){bv, bv, bv, bv};
        accn[0][n2] = (f32x4){nb, nb, nb, nb};
      }
      mmh<4>(u0, u1, WT(11), accc, t, nh);
      mmh<1>(&hA0, &hA1, WT(13), accn, t, nh);
      mmh<1>(k0, k1, WT(14), accn, t, nh);
#pragma unroll
      for (int n2 = 0; n2 < 2; ++n2) {
        const int col = (nh * 2 + n2) * 16 + c15;
        const float w2v = c_w2[col];
#pragma unroll
        for (int mt = 0; mt < 4; ++mt)
#pragma unroll
          for (int i = 0; i < 4; ++i)
            s[mt][i] += fmaxf(accc[mt][n2][i], 0.0f) * w2v;
#pragma unroll
        for (int i = 0; i < 4; ++i) {
          const int r = q * 4 + i;
          if (r < 5 || (r >= 8 && r < 13))
            TA[uswz(r, col)] = f2bf(fmaxf(accn[0][n2][i], 0.0f));
        }
      }
    }
#pragma unroll
    for (int mt = 0; mt < 4; ++mt)
#pragma unroll
      for (int i = 0; i < 4; ++i) {
        float ss = s[mt][i];
        ss += __shfl_xor(ss, 1, 64);
        ss += __shfl_xor(ss, 2, 64);
        ss += __shfl_xor(ss, 4, 64);
        ss += __shfl_xor(ss, 8, 64);
        svc[mt][i] = ss;
      }
  }
  fence();

  // ---------------- coord output (both graphs, VALU only) ----------------
  {
    const float vb2 = v_b2[0];
    float coutreg = 0.0f;
#pragma unroll
    for (int gsel = 0; gsel < 2; ++gsel) {
      const int lb = gsel * 32;
#pragma unroll
      for (int i = 0; i < 5; ++i) {
        const int rr = gsel * 8 + i;  // stacked VRED row
        const float vmi = rlane(svv[rr & 3], (rr >> 2) << 4) + vb2;
#pragma unroll
        for (int dd = 0; dd < 3; ++dd) {
          const float ci = rlane(scvreg, lb + i * 3 + dd);
          float s = 0.0f;
#pragma unroll
          for (int jj = 0; jj < 4; ++jj) {
            const int j = jj + (jj >= i ? 1 : 0);
            const int p = i * 4 + jj;
            const float cmp = rlane(svc[gsel * 2 + (p >> 4)][p & 3], ((p & 15) >> 2) << 4);
            float tr = (ci - rlane(scvreg, lb + j * 3 + dd)) * cmp;
            tr = fminf(fmaxf(tr, -100.0f), 100.0f);
            s += tr;
          }
          const float val = ci + 0.25f * s + rlane(scvreg, lb + 16 + i * 3 + dd) * vmi;
          if (t == lb + i * 3 + dd) coutreg = val;
        }
      }
    }
    if (t < 15) cout[gA * 15 + t] = coutreg;
    else if (t >= 32 && t < 47) cout[gB * 15 + (t - 32)] = coutreg;
  }

  // ---------------- node model L2 (stacked) + residual -> hout -------------
  {
    short8 a0[1], a1[1];
    loadA<1, 15>(TA, t, a0, a1);
#pragma unroll
    for (int nh = 0; nh < 2; ++nh) {
      f32x4 acc[1][2];
#pragma unroll
      for (int n2 = 0; n2 < 2; ++n2) {
        const float nb = n_b2[(nh * 2 + n2) * 16 + c15];
        acc[0][n2] = (f32x4){nb, nb, nb, nb};
      }
      mmh<1>(a0, a1, WT(15), acc, t, nh);
#pragma unroll
      for (int n2 = 0; n2 < 2; ++n2) {
        const int col = (nh * 2 + n2) * 16 + c15;
#pragma unroll
        for (int i = 0; i < 4; ++i) {
          const int r = q * 4 + i;
          if (r < 5) {
            const size_t ix = (size_t)(gA * 5 + r) * HD + col;
            hout[ix] = gh[ix] + acc[0][n2][i];
          } else if (r >= 8 && r < 13) {
            const size_t ix = (size_t)(gB * 5 + (r - 8)) * HD + col;
            hout[ix] = gh[ix] + acc[0][n2][i];
          }
        }
      }
    }
  }
#undef WT
}

extern "C" void kernel_launch(void* const* d_in, const int* in_sizes, int n_in,
                              void* d_out, int out_size, void* d_ws, size_t ws_size,
                              hipStream_t stream) {
  if (n_in < 27) return;
  const float* gh    = (const float*)d_in[0];
  const float* coord = (const float*)d_in[1];
  const float* vel   = (const float*)d_in[2];
  const float* e_w1 = (const float*)d_in[4];
  const float* e_b1 = (const float*)d_in[5];
  const float* e_w2 = (const float*)d_in[6];
  const float* e_b2 = (const float*)d_in[7];
  const float* n_w1 = (const float*)d_in[8];
  const float* n_b1 = (const float*)d_in[9];
  const float* n_w2 = (const float*)d_in[10];
  const float* n_b2 = (const float*)d_in[11];
  const float* c_w1 = (const float*)d_in[12];
  const float* c_b1 = (const float*)d_in[13];
  const float* c_w2 = (const float*)d_in[14];
  const float* v_w1 = (const float*)d_in[15];
  const float* v_b1 = (const float*)d_in[16];
  const float* v_w2 = (const float*)d_in[17];
  const float* v_b2 = (const float*)d_in[18];
  const float* ic_wef = (const float*)d_in[19];
  const float* ic_pat = (const float*)d_in[20];
  const float* br_w1 = (const float*)d_in[21];
  const float* br_b1 = (const float*)d_in[22];
  const float* br_w2 = (const float*)d_in[23];
  const float* br_b2 = (const float*)d_in[24];
  const float* out_w = (const float*)d_in[25];
  const float* out_b = (const float*)d_in[26];

  const int N = in_sizes[0] / HD;  // 100000
  const int B = N / 5;             // 20000 graphs
  float* hout = (float*)d_out;
  float* cout = (float*)d_out + (size_t)N * HD;
  u16* W = (u16*)d_ws;  // 16*4096 + 2048 u16 = 135168 B

  prepack<<<17, 256, 0, stream>>>(br_w1, br_w2, out_w, e_w1, e_w2, c_w1, v_w1,
                                  n_w1, n_w2, ic_wef, W);

  const int gpb = WPB * 2;  // graphs per block
  const int blocks = (B + gpb - 1) / gpb;
  egcl_mfma<<<blocks, 64 * WPB, 0, stream>>>(
      gh, coord, vel, W, e_w1, e_b1, e_b2, n_b1, n_b2, c_b1, c_w2, v_b1, v_w2,
      v_b2, ic_pat, br_b1, br_b2, out_b, hout, cout, B);
}

// Round 14
// 236.532 us; speedup vs baseline: 1.3722x; 1.0037x over previous
//
#include <hip/hip_runtime.h>
#include <math.h>

#define HD 64
#define WPB 2  // waves per block; each wave handles TWO graphs

typedef unsigned short u16;
typedef unsigned int u32;
typedef __attribute__((ext_vector_type(8))) short short8;
typedef __attribute__((ext_vector_type(4))) float f32x4;

__device__ __forceinline__ u16 f2bf(float f) {
  u32 r;
  asm("v_cvt_pk_bf16_f32 %0, %1, %2" : "=v"(r) : "v"(f), "v"(f));
  return (u16)r;
}
__device__ __forceinline__ u32 pk2(float lo, float hi) {
  u32 r;
  asm("v_cvt_pk_bf16_f32 %0, %1, %2" : "=v"(r) : "v"(lo), "v"(hi));
  return r;
}
__device__ __forceinline__ float bf2f(u16 x) {
  return __uint_as_float(((u32)x) << 16);
}
// Quadrant swizzle (validated R10): XOR row bits 2-3 into col bits 4-5.
__device__ __forceinline__ int uswz(int row, int col) {
  return (row << 6) | (col ^ (((row >> 2) & 3) << 4));
}
__device__ __forceinline__ float rlane(float v, int l) {
  return __uint_as_float(__builtin_amdgcn_readlane(__float_as_uint(v), l));
}
// Wave-local LDS fence (R9 race post-mortem): drains DS ops at buffer-reuse
// boundaries. In-window in-place matmuls are safe WITHOUT fences (write data
// depends on the reads via MFMA); only cross-phase reuse needs this.
__device__ __forceinline__ void fence() {
  asm volatile("s_waitcnt lgkmcnt(0)" ::: "memory");
}

template <int MT, int RMAX>
__device__ __forceinline__ void loadA(const u16* A_, int t, short8* a0, short8* a1) {
  const int q8 = (t >> 4) << 3;
#pragma unroll
  for (int mt = 0; mt < MT; ++mt) {
    int row = mt * 16 + (t & 15);
    row = row > RMAX ? RMAX : row;
    const int idx = uswz(row, q8);
    a0[mt] = *reinterpret_cast<const short8*>(A_ + idx);
    a1[mt] = *reinterpret_cast<const short8*>(A_ + (idx ^ 32));
  }
}

template <int MTT>
__device__ __forceinline__ void mmh(const short8* a0, const short8* a1,
                                    const u16* __restrict__ WT, f32x4 (*acc)[2],
                                    int t, int nh) {
  const int c15 = t & 15;
  const int q8 = (t >> 4) << 3;
  short8 b[2][2];
#pragma unroll
  for (int n2 = 0; n2 < 2; ++n2) {
    const int nt = nh * 2 + n2;
#pragma unroll
    for (int s = 0; s < 2; ++s)
      b[n2][s] = *reinterpret_cast<const short8*>(WT + (nt * 16 + c15) * 64 + s * 32 + q8);
  }
#pragma unroll
  for (int mt = 0; mt < MTT; ++mt) {
#pragma unroll
    for (int n2 = 0; n2 < 2; ++n2)
      acc[mt][n2] = __builtin_amdgcn_mfma_f32_16x16x32_bf16(a0[mt], b[n2][0], acc[mt][n2], 0, 0, 0);
#pragma unroll
    for (int n2 = 0; n2 < 2; ++n2)
      acc[mt][n2] = __builtin_amdgcn_mfma_f32_16x16x32_bf16(a1[mt], b[n2][1], acc[mt][n2], 0, 0, 0);
  }
}

// two-graph single-stream phase. EPI: 1=store, 2=relu, 3=relu*M, 4=relu + D.
template <int MT, int RMAX, int EPI>
__device__ __forceinline__ void run_phase2(const u16* AA, const u16* AB,
                                           u16* DA, u16* DB,
                                           const u16* MA, const u16* MB,
                                           const u16* __restrict__ WT,
                                           const float* __restrict__ bias,
                                           int t, int rowoff = 0) {
  const int c15 = t & 15, q = t >> 4;
  constexpr int rowlim = (MT == 2) ? 25 : 5;
  short8 a0[2 * MT], a1[2 * MT];
  loadA<MT, RMAX>(AA, t, a0, a1);
  loadA<MT, RMAX>(AB, t, a0 + MT, a1 + MT);
#pragma unroll
  for (int nh = 0; nh < 2; ++nh) {
    f32x4 acc[2 * MT][2];
#pragma unroll
    for (int n2 = 0; n2 < 2; ++n2) {
      const int col = (nh * 2 + n2) * 16 + c15;
      const float bb = bias ? bias[col] : 0.0f;
#pragma unroll
      for (int mt = 0; mt < 2 * MT; ++mt) acc[mt][n2] = (f32x4){bb, bb, bb, bb};
    }
    __builtin_amdgcn_s_setprio(1);
    mmh<2 * MT>(a0, a1, WT, acc, t, nh);
    __builtin_amdgcn_s_setprio(0);
#pragma unroll
    for (int n2 = 0; n2 < 2; ++n2) {
      const int col = (nh * 2 + n2) * 16 + c15;
#pragma unroll
      for (int mt = 0; mt < 2 * MT; ++mt) {
        u16* D_ = (mt < MT) ? DA : DB;
        const u16* M_ = (mt < MT) ? MA : MB;
        const int r0 = (mt % MT) * 16 + q * 4;
        const int bix = uswz(r0 + rowoff, col);
#pragma unroll
        for (int i = 0; i < 4; ++i) {
          if (r0 + i < rowlim) {
            const int ix = bix + i * 64;
            float v = acc[mt][n2][i];
            if (EPI >= 2) v = fmaxf(v, 0.0f);
            if (EPI == 3) v *= bf2f(M_[ix]);
            if (EPI == 4) v += bf2f(D_[ix]);
            D_[ix] = f2bf(v);
          }
        }
      }
    }
  }
}

// ---- pre-pass: pack weights to bf16 transposed [n][k] ----
__global__ __launch_bounds__(256) void prepack(
    const float* __restrict__ br_w1, const float* __restrict__ br_w2,
    const float* __restrict__ out_w, const float* __restrict__ e_w1,
    const float* __restrict__ e_w2, const float* __restrict__ c_w1,
    const float* __restrict__ v_w1, const float* __restrict__ n_w1,
    const float* __restrict__ n_w2, const float* __restrict__ ic_wef,
    u16* __restrict__ W) {
  const int m = blockIdx.x;
  if (m == 16) {
    for (int e = threadIdx.x; e < 2048; e += blockDim.x) {
      const int n = e >> 5, k = e & 31;
      W[16 * 4096 + e] = (k < 12) ? f2bf(ic_wef[k * 64 + n]) : (u16)0;
    }
    return;
  }
  const float* src;
  switch (m) {
    case 0: src = br_w1; break;
    case 1: src = br_w1 + 4096; break;
    case 2: src = br_w1 + 8192; break;
    case 3: src = br_w2; break;
    case 4: src = br_w2 + 4096; break;
    case 5: src = br_w2 + 8192; break;
    case 6: src = out_w; break;
    case 7: src = e_w1; break;
    case 8: src = e_w1 + 64 * 64; break;
    case 9: src = e_w1 + 129 * 64; break;
    case 10: src = e_w2; break;
    case 11: src = c_w1; break;
    case 12: src = v_w1; break;
    case 13: src = n_w1; break;
    case 14: src = n_w1 + 64 * 64; break;
    default: src = n_w2; break;
  }
  u16* dst = W + m * 4096;
  for (int e = threadIdx.x; e < 4096; e += blockDim.x) {
    const int n = e >> 6, k = e & 63;
    dst[e] = f2bf(src[k * 64 + n]);
  }
}

__global__ __launch_bounds__(64 * WPB, 2) void egcl_mfma(
    const float* __restrict__ gh, const float* __restrict__ gcoord,
    const float* __restrict__ gvel, const u16* __restrict__ Wg,
    const float* __restrict__ e_w1, const float* __restrict__ e_b1,
    const float* __restrict__ e_b2,
    const float* __restrict__ n_b1, const float* __restrict__ n_b2,
    const float* __restrict__ c_b1, const float* __restrict__ c_w2,
    const float* __restrict__ v_b1, const float* __restrict__ v_w2,
    const float* __restrict__ v_b2,
    const float* __restrict__ ic_pat,
    const float* __restrict__ br_b1, const float* __restrict__ br_b2,
    const float* __restrict__ out_b,
    float* __restrict__ hout, float* __restrict__ cout, int B) {
  // per wave: KA@0 KB@1600 TA@3200 TB@4800 UA@6400 UB@8000 (9600 u16 = 19200B)
  __shared__ __align__(16) u16 arena[WPB][9600];

  const int t = threadIdx.x & 63;
  const int wv = threadIdx.x >> 6;
  const int gA = (blockIdx.x * WPB + wv) * 2;
  if (gA >= B) return;
  int gB = gA + 1;
  if (gB >= B) gB = gA;  // duplicate work, identical writes: benign

  u16* AR = arena[wv];
  u16* KA = AR;           u16* KB = AR + 1600;
  u16* TA = AR + 3200;    u16* TB = AR + 4800;
  u16* UA = AR + 6400;    u16* UB = AR + 8000;
  u16* EFa = TA;  // EF staging in T buffers pre-first-use
  u16* EFb = TB;
  const int c15 = t & 15, q = t >> 4, q8 = q << 3;
#define WT(m) (Wg + (m) * 4096)

  // ---------------- prologue ----------------
  // stacked H A-frags in registers: rows 0-4 = gA nodes, 8-12 = gB nodes
  short8 hA0, hA1;
  {
    int nd = c15 & 7;
    nd = nd > 4 ? 4 : nd;
    const int gg = (c15 & 8) ? gB : gA;
    const float* hp = gh + (size_t)(gg * 5 + nd) * HD + q8;
    const float4 f0 = *reinterpret_cast<const float4*>(hp);
    const float4 f1 = *reinterpret_cast<const float4*>(hp + 4);
    const float4 f2 = *reinterpret_cast<const float4*>(hp + 32);
    const float4 f3 = *reinterpret_cast<const float4*>(hp + 36);
    union { u32 w[4]; short8 s; } u0, u1;
    u0.w[0] = pk2(f0.x, f0.y); u0.w[1] = pk2(f0.z, f0.w);
    u0.w[2] = pk2(f1.x, f1.y); u0.w[3] = pk2(f1.z, f1.w);
    u1.w[0] = pk2(f2.x, f2.y); u1.w[1] = pk2(f2.z, f2.w);
    u1.w[2] = pk2(f3.x, f3.y); u1.w[3] = pk2(f3.z, f3.w);
    hA0 = u0.s;
    hA1 = u1.s;
  }

  // scvreg lanes: 0-14 coordA, 16-30 velA, 32-46 coordB, 48-62 velB
  float scvreg = 0.0f;
  if (t < 15) scvreg = gcoord[gA * 15 + t];
  else if (t >= 16 && t < 31) scvreg = gvel[gA * 15 + (t - 16)];
  else if (t >= 32 && t < 47) scvreg = gcoord[gB * 15 + (t - 32)];
  else if (t >= 48 && t < 63) scvreg = gvel[gB * 15 + (t - 48)];

  // zero EF cols 12..31 for both graphs
#pragma unroll
  for (int z = 0; z < 8; ++z) {
    const int e = t + z * 64;
    if (e < 500) {
      const int gsel = e >= 250;
      const int ee = e - gsel * 250;
      const int row = ee / 10, cc = 12 + (ee % 10) * 2;
      *reinterpret_cast<u32*>((gsel ? EFb : EFa) + row * 32 + cc) = 0u;
    }
  }

  // RBF: lanes 0-24 = graph A tuples, lanes 32-56 = graph B tuples
  float sqcc = 0.0f;
  {
    const int lb = (t >= 32) ? 32 : 0;
    const int tt = t - lb;
    if (tt < 25) {
      u16* EF = lb ? EFb : EFa;
      const int ti = tt / 5, tj = tt % 5;
      const float cix = __shfl(scvreg, lb + ti * 3 + 0, 64), ciy = __shfl(scvreg, lb + ti * 3 + 1, 64), ciz = __shfl(scvreg, lb + ti * 3 + 2, 64);
      const float cjx = __shfl(scvreg, lb + tj * 3 + 0, 64), cjy = __shfl(scvreg, lb + tj * 3 + 1, 64), cjz = __shfl(scvreg, lb + tj * 3 + 2, 64);
      const float vix = __shfl(scvreg, lb + 16 + ti * 3 + 0, 64), viy = __shfl(scvreg, lb + 16 + ti * 3 + 1, 64), viz = __shfl(scvreg, lb + 16 + ti * 3 + 2, 64);
      const float vjx = __shfl(scvreg, lb + 16 + tj * 3 + 0, 64), vjy = __shfl(scvreg, lb + 16 + tj * 3 + 1, 64), vjz = __shfl(scvreg, lb + 16 + tj * 3 + 2, 64);
      {
        const float dx = cix - cjx, dy = ciy - cjy, dz = ciz - cjz;
        sqcc = dx * dx + dy * dy + dz * dz;
      }
      auto sd = [](float sq) { return (sq > 0.0f) ? sqrtf(sq) : 0.0f; };
      float sq2;
      const float dcc = sd(sqcc);
      {
        const float dx = vix - vjx, dy = viy - vjy, dz = viz - vjz;
        sq2 = dx * dx + dy * dy + dz * dz;
      }
      const float dvv = sd(sq2);
      {
        const float dx = cix - vjx, dy = ciy - vjy, dz = ciz - vjz;
        sq2 = dx * dx + dy * dy + dz * dz;
      }
      const float dcv = sd(sq2);
      {
        const float dx = cjx - vix, dy = cjy - viy, dz = cjz - viz;
        sq2 = dx * dx + dy * dy + dz * dz;
      }
      const float dvc = sd(sq2);
      auto rbf3 = [&](float d, int base) {
        const float cut = (d <= 10.0f) ? (0.5f * (cosf(d * 0.31415926535897931f) + 1.0f)) : 0.0f;
        const float e = expf(-0.5f * d);
        const float u0 = e - 4.5399929762484854e-05f;
        const float u1 = e - 0.50002270f;
        const float u2 = e - 1.0f;
        const float BETA = 2.2502043f;
        EF[tt * 32 + base + 0] = f2bf((cut * expf(-BETA * u0 * u0) - 0.05f) * (1.0f / 0.15f));
        EF[tt * 32 + base + 1] = f2bf((cut * expf(-BETA * u1 * u1) - 0.05f) * (1.0f / 0.15f));
        EF[tt * 32 + base + 2] = f2bf((cut * expf(-BETA * u2 * u2) - 0.05f) * (1.0f / 0.15f));
      };
      rbf3(dcc, 0);
      rbf3(dvv, 3);
      rbf3(dcv, 6);
      rbf3(dvc, 9);
    }
  }
  fence();

  // ---------------- kemb (both graphs) -> KA/KB ----------------
  {
    short8 aE[4];
#pragma unroll
    for (int gsel = 0; gsel < 2; ++gsel) {
      const u16* EF = gsel ? EFb : EFa;
#pragma unroll
      for (int mt = 0; mt < 2; ++mt) {
        int row = mt * 16 + c15;
        row = row > 24 ? 24 : row;
        aE[gsel * 2 + mt] = *reinterpret_cast<const short8*>(EF + row * 32 + q8);
      }
    }
    const u16* WTp = Wg + 16 * 4096;
#pragma unroll
    for (int nh = 0; nh < 2; ++nh) {
      f32x4 acc[4][2];
#pragma unroll
      for (int mt = 0; mt < 4; ++mt)
#pragma unroll
        for (int n2 = 0; n2 < 2; ++n2) acc[mt][n2] = (f32x4){0.f, 0.f, 0.f, 0.f};
      short8 b[2];
#pragma unroll
      for (int n2 = 0; n2 < 2; ++n2)
        b[n2] = *reinterpret_cast<const short8*>(WTp + ((nh * 2 + n2) * 16 + c15) * 32 + q8);
      __builtin_amdgcn_s_setprio(1);
#pragma unroll
      for (int mt = 0; mt < 4; ++mt)
#pragma unroll
        for (int n2 = 0; n2 < 2; ++n2)
          acc[mt][n2] = __builtin_amdgcn_mfma_f32_16x16x32_bf16(aE[mt], b[n2], acc[mt][n2], 0, 0, 0);
      __builtin_amdgcn_s_setprio(0);
#pragma unroll
      for (int n2 = 0; n2 < 2; ++n2) {
        const int col = (nh * 2 + n2) * 16 + c15;
        const float p1 = ic_pat[64 + col], p2 = ic_pat[128 + col];
#pragma unroll
        for (int mt = 0; mt < 4; ++mt) {
          u16* K_ = (mt < 2) ? KA : KB;
          const int r0 = (mt & 1) * 16 + q * 4;
          const int bix = uswz(r0, col);
#pragma unroll
          for (int i = 0; i < 4; ++i) {
            const int row = r0 + i;
            if (row < 25) {
              const bool diag = (row % 6) == 0;
              K_[bix + i * 64] = f2bf(acc[mt][n2][i] * (diag ? p2 : p1));
            }
          }
        }
      }
    }
  }
  fence();

  // -------- Window A: k0L1 (W1) K->T  ||  k1L1 (W2) K->U  (shared A) -------
  {
    short8 a0[4], a1[4];
    loadA<2, 24>(KA, t, a0, a1);
    loadA<2, 24>(KB, t, a0 + 2, a1 + 2);
#pragma unroll
    for (int nh = 0; nh < 2; ++nh) {
      f32x4 ac0[4][2], ac1[4][2];
#pragma unroll
      for (int n2 = 0; n2 < 2; ++n2) {
        const int col = (nh * 2 + n2) * 16 + c15;
        const float b0 = br_b1[64 + col], b1 = br_b1[128 + col];
#pragma unroll
        for (int mt = 0; mt < 4; ++mt) {
          ac0[mt][n2] = (f32x4){b0, b0, b0, b0};
          ac1[mt][n2] = (f32x4){b1, b1, b1, b1};
        }
      }
      __builtin_amdgcn_s_setprio(1);
      mmh<4>(a0, a1, WT(1), ac0, t, nh);
      mmh<4>(a0, a1, WT(2), ac1, t, nh);
      __builtin_amdgcn_s_setprio(0);
#pragma unroll
      for (int n2 = 0; n2 < 2; ++n2) {
        const int col = (nh * 2 + n2) * 16 + c15;
#pragma unroll
        for (int mt = 0; mt < 4; ++mt) {
          u16* T_ = (mt < 2) ? TA : TB;
          u16* U_ = (mt < 2) ? UA : UB;
          const int r0 = (mt & 1) * 16 + q * 4;
          const int bix = uswz(r0, col);
#pragma unroll
          for (int i = 0; i < 4; ++i) {
            if (r0 + i < 25) {
              T_[bix + i * 64] = f2bf(fmaxf(ac0[mt][n2][i], 0.0f));
              U_[bix + i * 64] = f2bf(fmaxf(ac1[mt][n2][i], 0.0f));
            }
          }
        }
      }
    }
  }
  fence();

  // -------- Window B: k0L2 (W4) T->T  ||  k1L2 (W5) U->U  (in-place) -------
  {
    short8 a0[4], a1[4], c0[4], c1[4];
    loadA<2, 24>(TA, t, a0, a1);
    loadA<2, 24>(TB, t, a0 + 2, a1 + 2);
    loadA<2, 24>(UA, t, c0, c1);
    loadA<2, 24>(UB, t, c0 + 2, c1 + 2);
#pragma unroll
    for (int nh = 0; nh < 2; ++nh) {
      f32x4 ac0[4][2], ac1[4][2];
#pragma unroll
      for (int n2 = 0; n2 < 2; ++n2) {
        const int col = (nh * 2 + n2) * 16 + c15;
        const float b0 = br_b2[64 + col], b1 = br_b2[128 + col];
#pragma unroll
        for (int mt = 0; mt < 4; ++mt) {
          ac0[mt][n2] = (f32x4){b0, b0, b0, b0};
          ac1[mt][n2] = (f32x4){b1, b1, b1, b1};
        }
      }
      __builtin_amdgcn_s_setprio(1);
      mmh<4>(a0, a1, WT(4), ac0, t, nh);
      mmh<4>(c0, c1, WT(5), ac1, t, nh);
      __builtin_amdgcn_s_setprio(0);
#pragma unroll
      for (int n2 = 0; n2 < 2; ++n2) {
        const int col = (nh * 2 + n2) * 16 + c15;
#pragma unroll
        for (int mt = 0; mt < 4; ++mt) {
          u16* T_ = (mt < 2) ? TA : TB;
          u16* U_ = (mt < 2) ? UA : UB;
          const int r0 = (mt & 1) * 16 + q * 4;
          const int bix = uswz(r0, col);
#pragma unroll
          for (int i = 0; i < 4; ++i) {
            if (r0 + i < 25) {
              T_[bix + i * 64] = f2bf(fmaxf(ac0[mt][n2][i], 0.0f));
              U_[bix + i * 64] = f2bf(fmaxf(ac1[mt][n2][i], 0.0f));
            }
          }
        }
      }
    }
  }
  fence();

  // ---------------- einsum (both graphs): mult = k0(T) @ k1(U) -> U --------
  {
    float mu[2][25];
#pragma unroll
    for (int gsel = 0; gsel < 2; ++gsel)
#pragma unroll
      for (int p = 0; p < 25; ++p) mu[gsel][p] = 0.0f;
#pragma unroll
    for (int j = 0; j < 5; ++j) {
#pragma unroll
      for (int gsel = 0; gsel < 2; ++gsel) {
        const u16* Tg = gsel ? TB : TA;
        const u16* Ug = gsel ? UB : UA;
        float k1r[5], k0c[5];
#pragma unroll
        for (int k = 0; k < 5; ++k) k1r[k] = bf2f(Ug[uswz(j * 5 + k, t)]);
#pragma unroll
        for (int i = 0; i < 5; ++i) k0c[i] = bf2f(Tg[uswz(i * 5 + j, t)]);
#pragma unroll
        for (int i = 0; i < 5; ++i)
#pragma unroll
          for (int k = 0; k < 5; ++k)
            mu[gsel][i * 5 + k] = fmaf(k0c[i], k1r[k], mu[gsel][i * 5 + k]);
      }
    }
    fence();  // all T/U reads returned before U overwrite
#pragma unroll
    for (int p = 0; p < 25; ++p) {
      UA[uswz(p, t)] = f2bf(mu[0][p]);
      UB[uswz(p, t)] = f2bf(mu[1][p]);
    }
  }
  fence();

  run_phase2<2, 24, 2>(KA, KB, TA, TB, nullptr, nullptr, WT(0), br_b1, t); fence();  // smL1 K->T
  run_phase2<2, 24, 3>(TA, TB, TA, TB, UA, UB, WT(3), br_b2, t); fence();            // z = relu(sm)*mult -> T
  run_phase2<2, 24, 4>(TA, TB, KA, KB, nullptr, nullptr, WT(6), out_b, t); fence();  // residual -> K

  // ------ Window F: accC (W9) K->T || stacked-H (W7,W8->U; W12 VRED) -------
  float svv[4];
  {
    short8 a0[4], a1[4];
    loadA<2, 24>(KA, t, a0, a1);
    loadA<2, 24>(KB, t, a0 + 2, a1 + 2);
    float s[4] = {0.f, 0.f, 0.f, 0.f};
#pragma unroll
    for (int nh = 0; nh < 2; ++nh) {
      f32x4 accC[4][2], aA[1][2], aB[1][2], aV[1][2];
#pragma unroll
      for (int n2 = 0; n2 < 2; ++n2) {
        const float bv = v_b1[(nh * 2 + n2) * 16 + c15];
#pragma unroll
        for (int mt = 0; mt < 4; ++mt) accC[mt][n2] = (f32x4){0.f, 0.f, 0.f, 0.f};
        aA[0][n2] = (f32x4){0.f, 0.f, 0.f, 0.f};
        aB[0][n2] = (f32x4){0.f, 0.f, 0.f, 0.f};
        aV[0][n2] = (f32x4){bv, bv, bv, bv};
      }
      __builtin_amdgcn_s_setprio(1);
      mmh<4>(a0, a1, WT(9), accC, t, nh);
      mmh<1>(&hA0, &hA1, WT(7), aA, t, nh);
      mmh<1>(&hA0, &hA1, WT(8), aB, t, nh);
      mmh<1>(&hA0, &hA1, WT(12), aV, t, nh);
      __builtin_amdgcn_s_setprio(0);
#pragma unroll
      for (int n2 = 0; n2 < 2; ++n2) {
        const int col = (nh * 2 + n2) * 16 + c15;
        const float w2v = v_w2[col];
#pragma unroll
        for (int mt = 0; mt < 4; ++mt) {  // accC -> T (store, no relu)
          u16* T_ = (mt < 2) ? TA : TB;
          const int r0 = (mt & 1) * 16 + q * 4;
          const int bix = uswz(r0, col);
#pragma unroll
          for (int i = 0; i < 4; ++i)
            if (r0 + i < 25) T_[bix + i * 64] = f2bf(accC[mt][n2][i]);
        }
#pragma unroll
        for (int i = 0; i < 4; ++i) {  // stacked accA/accB -> U, VRED partial
          const int r = q * 4 + i;
          if (r < 5) {
            UA[uswz(r, col)] = f2bf(aA[0][n2][i]);
            UA[uswz(r + 8, col)] = f2bf(aB[0][n2][i]);
          } else if (r >= 8 && r < 13) {
            UB[uswz(r - 8, col)] = f2bf(aA[0][n2][i]);
            UB[uswz(r, col)] = f2bf(aB[0][n2][i]);
          }
          s[i] += fmaxf(aV[0][n2][i], 0.0f) * w2v;
        }
      }
    }
#pragma unroll
    for (int i = 0; i < 4; ++i) {
      float ss = s[i];
      ss += __shfl_xor(ss, 1, 64);
      ss += __shfl_xor(ss, 2, 64);
      ss += __shfl_xor(ss, 4, 64);
      ss += __shfl_xor(ss, 8, 64);
      svv[i] = ss;  // stacked: gA node i at row i, gB node i at row 8+i
    }
  }
  fence();

  // ---------------- edge assembly (both graphs) ----------------
  {
    float ec[2][20];
#pragma unroll
    for (int gsel = 0; gsel < 2; ++gsel) {
      const int lb = gsel * 32;
      const u16* Ug = gsel ? UB : UA;
      const u16* Tg = gsel ? TB : TA;
      float aAc[5], aBc[5];
#pragma unroll
      for (int i = 0; i < 5; ++i) {
        aAc[i] = bf2f(Ug[uswz(i, t)]);
        aBc[i] = bf2f(Ug[uswz(8 + i, t)]);
      }
      const float eb1v = e_b1[t];
      const float wradv = e_w1[128 * HD + t];
#pragma unroll
      for (int p = 0; p < 20; ++p) {
        const int i = p >> 2, jj = p & 3;
        const int j = jj + (jj >= i ? 1 : 0);
        const float radial = rlane(sqcc, lb + i * 5 + j);
        const float cc = bf2f(Tg[uswz(i * 5 + j, t)]);
        ec[gsel][p] = fmaxf(aAc[i] + aBc[j] + radial * wradv + cc + eb1v, 0.0f);
      }
    }
    fence();  // reads returned before T overwrite
#pragma unroll
    for (int p = 0; p < 20; ++p) {
      TA[uswz(p, t)] = f2bf(ec[0][p]);
      TB[uswz(p, t)] = f2bf(ec[1][p]);
    }
  }
  fence();

  // ------ Window G: edge_feat (W10) T->U with FUSED nagg -> KA rows --------
  {
    short8 a0[4], a1[4];
    loadA<2, 24>(TA, t, a0, a1);
    loadA<2, 24>(TB, t, a0 + 2, a1 + 2);
#pragma unroll
    for (int nh = 0; nh < 2; ++nh) {
      f32x4 acc[4][2];
#pragma unroll
      for (int n2 = 0; n2 < 2; ++n2) {
        const float bb = e_b2[(nh * 2 + n2) * 16 + c15];
#pragma unroll
        for (int mt = 0; mt < 4; ++mt) acc[mt][n2] = (f32x4){bb, bb, bb, bb};
      }
      __builtin_amdgcn_s_setprio(1);
      mmh<4>(a0, a1, WT(10), acc, t, nh);
      __builtin_amdgcn_s_setprio(0);
#pragma unroll
      for (int n2 = 0; n2 < 2; ++n2) {
        const int col = (nh * 2 + n2) * 16 + c15;
#pragma unroll
        for (int mt = 0; mt < 4; ++mt) {
          u16* U_ = (mt < 2) ? UA : UB;
          const int gsel = mt >> 1;
          const int r0 = (mt & 1) * 16 + q * 4;
          const int bix = uswz(r0, col);
          float na = 0.0f;
#pragma unroll
          for (int i = 0; i < 4; ++i) {
            const float v = fmaxf(acc[mt][n2][i], 0.0f);
            if (r0 + i < 25) U_[bix + i * 64] = f2bf(v);
            na += v;
          }
          // nagg: tile0 -> node q; tile1 (rows 16-19, q==0) -> node 4
          if (!(mt & 1)) {
            KA[uswz(gsel * 8 + q, col)] = f2bf(na);
          } else if (q == 0) {
            KA[uswz(gsel * 8 + 4, col)] = f2bf(na);
          }
        }
      }
    }
  }
  fence();

  // ------ Window CR: CRED (W11) U->svc  ||  nodeL1 (W13 H + W14 Knagg)->T --
  float svcA[2][4], svcB[2][4];
  {
    short8 u0[4], u1[4], k0[1], k1[1];
    loadA<2, 24>(UA, t, u0, u1);
    loadA<2, 24>(UB, t, u0 + 2, u1 + 2);
    loadA<1, 15>(KA, t, k0, k1);  // stacked nagg (garbage rows harmless)
    float s[4][4];
#pragma unroll
    for (int mt = 0; mt < 4; ++mt)
#pragma unroll
      for (int i = 0; i < 4; ++i) s[mt][i] = 0.0f;
#pragma unroll
    for (int nh = 0; nh < 2; ++nh) {
      f32x4 accc[4][2], accn[1][2];
#pragma unroll
      for (int n2 = 0; n2 < 2; ++n2) {
        const int col = (nh * 2 + n2) * 16 + c15;
        const float bv = c_b1[col];
        const float nb = n_b1[col];
#pragma unroll
        for (int mt = 0; mt < 4; ++mt) accc[mt][n2] = (f32x4){bv, bv, bv, bv};
        accn[0][n2] = (f32x4){nb, nb, nb, nb};
      }
      __builtin_amdgcn_s_setprio(1);
      mmh<4>(u0, u1, WT(11), accc, t, nh);
      mmh<1>(&hA0, &hA1, WT(13), accn, t, nh);
      mmh<1>(k0, k1, WT(14), accn, t, nh);
      __builtin_amdgcn_s_setprio(0);
#pragma unroll
      for (int n2 = 0; n2 < 2; ++n2) {
        const int col = (nh * 2 + n2) * 16 + c15;
        const float w2v = c_w2[col];
#pragma unroll
        for (int mt = 0; mt < 4; ++mt)
#pragma unroll
          for (int i = 0; i < 4; ++i)
            s[mt][i] += fmaxf(accc[mt][n2][i], 0.0f) * w2v;
#pragma unroll
        for (int i = 0; i < 4; ++i) {
          const int r = q * 4 + i;
          if (r < 5 || (r >= 8 && r < 13))
            TA[uswz(r, col)] = f2bf(fmaxf(accn[0][n2][i], 0.0f));
        }
      }
    }
#pragma unroll
    for (int mt = 0; mt < 4; ++mt)
#pragma unroll
      for (int i = 0; i < 4; ++i) {
        float ss = s[mt][i];
        ss += __shfl_xor(ss, 1, 64);
        ss += __shfl_xor(ss, 2, 64);
        ss += __shfl_xor(ss, 4, 64);
        ss += __shfl_xor(ss, 8, 64);
        if (mt < 2) svcA[mt][i] = ss; else svcB[mt - 2][i] = ss;
      }
  }
  fence();

  // ------- coord output (lane-parallel: lanes 0-14 gA, 32-46 gB) -----------
  {
    const float vb2 = v_b2[0];
    const int lb = (t >= 32) ? 32 : 0;
    const int tt = t - lb;  // 0..14 active
    const int gsel = lb ? 1 : 0;
    int ii = tt / 3;
    if (ii > 4) ii = 4;  // inactive lanes: clamp for sane shfl indices
    const int dd = tt - (tt / 3) * 3;
    const int rr = gsel * 8 + ii;
    const int sl = (rr >> 2) << 4;
    // vmi = svv[rr&3] @ lane sl  (shuffle all candidates, then select)
    const float w0 = __shfl(svv[0], sl, 64);
    const float w1 = __shfl(svv[1], sl, 64);
    const float w2 = __shfl(svv[2], sl, 64);
    const float w3 = __shfl(svv[3], sl, 64);
    float vsel = w0;
    vsel = ((rr & 3) == 1) ? w1 : vsel;
    vsel = ((rr & 3) == 2) ? w2 : vsel;
    vsel = ((rr & 3) == 3) ? w3 : vsel;
    const float vmi = vsel + vb2;
    const float ci = scvreg;                              // own lane = lb+ii*3+dd
    const float vel_ = __shfl(scvreg, lb + 16 + tt, 64);  // matching vel
    const bool i4 = (ii == 4);
    const int cl = i4 ? 0 : (ii << 4);
    float ssum = 0.0f;
#pragma unroll
    for (int jj = 0; jj < 4; ++jj) {
      const int j = jj + (jj >= ii ? 1 : 0);
      const float a0 = __shfl(svcA[0][jj], cl, 64);
      const float a1 = __shfl(svcA[1][jj], cl, 64);
      const float b0 = __shfl(svcB[0][jj], cl, 64);
      const float b1 = __shfl(svcB[1][jj], cl, 64);
      const float cmp = gsel ? (i4 ? b1 : b0) : (i4 ? a1 : a0);
      const float cj = __shfl(scvreg, lb + j * 3 + dd, 64);
      float tr = (ci - cj) * cmp;
      tr = fminf(fmaxf(tr, -100.0f), 100.0f);
      ssum += tr;
    }
    const float val = ci + 0.25f * ssum + vel_ * vmi;
    if (t < 15) cout[gA * 15 + t] = val;
    else if (t >= 32 && t < 47) cout[gB * 15 + (t - 32)] = val;
  }

  // ---------------- node model L2 (stacked) + residual -> hout -------------
  {
    short8 a0[1], a1[1];
    loadA<1, 15>(TA, t, a0, a1);
#pragma unroll
    for (int nh = 0; nh < 2; ++nh) {
      f32x4 acc[1][2];
#pragma unroll
      for (int n2 = 0; n2 < 2; ++n2) {
        const float nb = n_b2[(nh * 2 + n2) * 16 + c15];
        acc[0][n2] = (f32x4){nb, nb, nb, nb};
      }
      __builtin_amdgcn_s_setprio(1);
      mmh<1>(a0, a1, WT(15), acc, t, nh);
      __builtin_amdgcn_s_setprio(0);
#pragma unroll
      for (int n2 = 0; n2 < 2; ++n2) {
        const int col = (nh * 2 + n2) * 16 + c15;
#pragma unroll
        for (int i = 0; i < 4; ++i) {
          const int r = q * 4 + i;
          if (r < 5) {
            const size_t ix = (size_t)(gA * 5 + r) * HD + col;
            hout[ix] = gh[ix] + acc[0][n2][i];
          } else if (r >= 8 && r < 13) {
            const size_t ix = (size_t)(gB * 5 + (r - 8)) * HD + col;
            hout[ix] = gh[ix] + acc[0][n2][i];
          }
        }
      }
    }
  }
#undef WT
}

extern "C" void kernel_launch(void* const* d_in, const int* in_sizes, int n_in,
                              void* d_out, int out_size, void* d_ws, size_t ws_size,
                              hipStream_t stream) {
  if (n_in < 27) return;
  const float* gh    = (const float*)d_in[0];
  const float* coord = (const float*)d_in[1];
  const float* vel   = (const float*)d_in[2];
  const float* e_w1 = (const float*)d_in[4];
  const float* e_b1 = (const float*)d_in[5];
  const float* e_w2 = (const float*)d_in[6];
  const float* e_b2 = (const float*)d_in[7];
  const float* n_w1 = (const float*)d_in[8];
  const float* n_b1 = (const float*)d_in[9];
  const float* n_w2 = (const float*)d_in[10];
  const float* n_b2 = (const float*)d_in[11];
  const float* c_w1 = (const float*)d_in[12];
  const float* c_b1 = (const float*)d_in[13];
  const float* c_w2 = (const float*)d_in[14];
  const float* v_w1 = (const float*)d_in[15];
  const float* v_b1 = (const float*)d_in[16];
  const float* v_w2 = (const float*)d_in[17];
  const float* v_b2 = (const float*)d_in[18];
  const float* ic_wef = (const float*)d_in[19];
  const float* ic_pat = (const float*)d_in[20];
  const float* br_w1 = (const float*)d_in[21];
  const float* br_b1 = (const float*)d_in[22];
  const float* br_w2 = (const float*)d_in[23];
  const float* br_b2 = (const float*)d_in[24];
  const float* out_w = (const float*)d_in[25];
  const float* out_b = (const float*)d_in[26];

  const int N = in_sizes[0] / HD;  // 100000
  const int B = N / 5;             // 20000 graphs
  float* hout = (float*)d_out;
  float* cout = (float*)d_out + (size_t)N * HD;
  u16* W = (u16*)d_ws;  // 16*4096 + 2048 u16 = 135168 B

  prepack<<<17, 256, 0, stream>>>(br_w1, br_w2, out_w, e_w1, e_w2, c_w1, v_w1,
                                  n_w1, n_w2, ic_wef, W);

  const int gpb = WPB * 2;  // graphs per block
  const int blocks = (B + gpb - 1) / gpb;
  egcl_mfma<<<blocks, 64 * WPB, 0, stream>>>(
      gh, coord, vel, W, e_w1, e_b1, e_b2, n_b1, n_b2, c_b1, c_w2, v_b1, v_w2,
      v_b2, ic_pat, br_b1, br_b2, out_b, hout, cout, B);
}